// Round 1
// baseline (1593.020 us; speedup 1.0000x reference)
//
#include <hip/hip_runtime.h>
#include <hip/hip_bf16.h>
#include <math.h>

#define T_   2048
#define C_   2048
#define H_   16
#define N_   128
#define KVH_ 4

typedef __bf16 bf16x8 __attribute__((ext_vector_type(8)));
typedef __bf16 bf16x4 __attribute__((ext_vector_type(4)));
typedef float  f32x4  __attribute__((ext_vector_type(4)));

// ---------------- DPP wave64 all-reduce (no DS ops) ----------------
template <int CTRL>
static __device__ __forceinline__ float dpp_add(float x) {
    int y = __builtin_amdgcn_update_dpp(0, __float_as_int(x), CTRL, 0xF, 0xF, true);
    return x + __int_as_float(y);
}
static __device__ __forceinline__ float wave64_allsum(float x) {
    x = dpp_add<0xB1>(x);   // quad_perm [1,0,3,2]  (xor 1)
    x = dpp_add<0x4E>(x);   // quad_perm [2,3,0,1]  (xor 2)
    x = dpp_add<0x141>(x);  // row_half_mirror      (xor 4 equiv)
    x = dpp_add<0x140>(x);  // row_mirror           (xor 8 equiv)
    x = dpp_add<0x142>(x);  // row_bcast15
    x = dpp_add<0x143>(x);  // row_bcast31  -> lane 63 has full sum
    return __int_as_float(__builtin_amdgcn_readlane(__float_as_int(x), 63));
}

static __device__ __forceinline__ float wave_sum_shfl(float v) {
#pragma unroll
    for (int m = 32; m >= 1; m >>= 1) v += __shfl_xor(v, m, 64);
    return v;
}

// block of 128 threads: sum over all 128 lanes (uses sh2[2])
static __device__ __forceinline__ float block_sum_128(float v, float* sh2) {
    v = wave_sum_shfl(v);
    if ((threadIdx.x & 63) == 0) sh2[threadIdx.x >> 6] = v;
    __syncthreads();
    float r = sh2[0] + sh2[1];
    __syncthreads();
    return r;
}

// ---------------- xm = bf16(x * mask) ----------------
__global__ void xm_to_bf16(const float* __restrict__ x, const float* __restrict__ mask,
                           __bf16* __restrict__ o) {
    int idx = blockIdx.x * 256 + threadIdx.x;  // one thread per 4 elems
    int e = idx * 4;
    float4 v = *(const float4*)(x + e);
    float m = mask[e >> 11];  // row = e / 2048
    bf16x4 r;
    r.x = (__bf16)(v.x * m); r.y = (__bf16)(v.y * m);
    r.z = (__bf16)(v.z * m); r.w = (__bf16)(v.w * m);
    *(bf16x4*)(o + e) = r;
}

// ---------------- tiled transpose f32 (R x C) -> bf16 (C x R) ----------------
__global__ void transpose_f32_bf16(const float* __restrict__ src, __bf16* __restrict__ dst,
                                   int R, int C) {
    __shared__ float tile[32][33];
    int tx = threadIdx.x & 31, ty = threadIdx.x >> 5;  // 32 x 8
    int c0 = blockIdx.x * 32, r0 = blockIdx.y * 32;
#pragma unroll
    for (int i = 0; i < 4; i++) {
        int r = r0 + ty + i * 8, c = c0 + tx;
        if (r < R && c < C) tile[ty + i * 8][tx] = src[(size_t)r * C + c];
    }
    __syncthreads();
#pragma unroll
    for (int i = 0; i < 4; i++) {
        int c = c0 + ty + i * 8, r = r0 + tx;
        if (c < C && r < R) dst[(size_t)c * R + r] = (__bf16)tile[tx][ty + i * 8];
    }
}

// ---------------- MFMA GEMM: C[M,N] = A[M,K] @ BT[N,K]^T ----------------
// M == 2048 (multiple of 128), K multiple of 32. N arbitrary (bounds-checked).
// act: 0 none, 1 tanh, 2 sigmoid.  out = act(acc + bias[n])
__global__ __launch_bounds__(256, 2)
void gemm_bf16_bt(const __bf16* __restrict__ A, const __bf16* __restrict__ BT,
                  const float* __restrict__ bias, float* __restrict__ Cf,
                  __bf16* __restrict__ Cb, int N, int K, int act) {
    constexpr int LDK = 40;  // 32 + 8 bf16 pad (16B) -> stride 80B = 20 banks
    __shared__ __align__(16) __bf16 As[128 * LDK];
    __shared__ __align__(16) __bf16 Bs[128 * LDK];
    const int tid = threadIdx.x;
    const int lane = tid & 63, wave = tid >> 6;
    const int bm = blockIdx.y * 128, bn = blockIdx.x * 128;
    const int wm = (wave >> 1) * 64, wn = (wave & 1) * 64;
    const int srow = tid >> 1;
    const int skoff = (tid & 1) * 16;
    const __bf16* Ap = A + (size_t)(bm + srow) * K + skoff;
    const __bf16* Bp = BT + (size_t)(bn + srow) * K + skoff;
    const bool bok = (bn + srow) < N;
    __bf16* AsW = As + srow * LDK + skoff;
    __bf16* BsW = Bs + srow * LDK + skoff;
    const int lm = lane & 15, lq = lane >> 4;
    f32x4 acc[4][4] = {};
    for (int k0 = 0; k0 < K; k0 += 32) {
        int4 a0 = *(const int4*)(Ap);
        int4 a1 = *(const int4*)(Ap + 8);
        int4 b0 = {0, 0, 0, 0}, b1 = {0, 0, 0, 0};
        if (bok) { b0 = *(const int4*)(Bp); b1 = *(const int4*)(Bp + 8); }
        __syncthreads();
        *(int4*)(AsW) = a0; *(int4*)(AsW + 8) = a1;
        *(int4*)(BsW) = b0; *(int4*)(BsW + 8) = b1;
        __syncthreads();
        bf16x8 af[4], bf[4];
#pragma unroll
        for (int i = 0; i < 4; i++)
            af[i] = *(const bf16x8*)(As + (wm + i * 16 + lm) * LDK + lq * 8);
#pragma unroll
        for (int j = 0; j < 4; j++)
            bf[j] = *(const bf16x8*)(Bs + (wn + j * 16 + lm) * LDK + lq * 8);
#pragma unroll
        for (int i = 0; i < 4; i++)
#pragma unroll
            for (int j = 0; j < 4; j++)
                acc[i][j] = __builtin_amdgcn_mfma_f32_16x16x32_bf16(af[i], bf[j], acc[i][j], 0, 0, 0);
        Ap += 32; Bp += 32;
    }
    // epilogue: D row = (lane>>4)*4 + reg, col = lane&15   [m89/m91 layout]
#pragma unroll
    for (int j = 0; j < 4; j++) {
        int col = bn + wn + j * 16 + lm;
        if (col >= N) continue;
        float bv = bias ? bias[col] : 0.f;
#pragma unroll
        for (int i = 0; i < 4; i++) {
            int row0 = bm + wm + i * 16 + lq * 4;
#pragma unroll
            for (int rg = 0; rg < 4; rg++) {
                float v = acc[i][j][rg] + bv;
                if (act == 1) v = tanhf(v);
                else if (act == 2) v = 1.f / (1.f + __expf(-v));
                size_t off = (size_t)(row0 + rg) * N + col;
                if (Cf) Cf[off] = v;
                if (Cb) Cb[off] = (__bf16)v;
            }
        }
    }
}

// ---------------- prep for k/v (per (t,kvh)) ----------------
__global__ __launch_bounds__(128)
void prep_kv(float* __restrict__ Kl,   // in: K_lin, out: k_fin   (T,KVH*N)
             float* __restrict__ Vl,   // in: V_lin, out: v_fin
             float* __restrict__ kkO,  // out: kk
             const float* __restrict__ kfirst, const float* __restrict__ vfirst,
             const float* __restrict__ kmix, const float* __restrict__ vmix,
             const float* __restrict__ cosT, const float* __restrict__ sinT,
             const float* __restrict__ knw) {
    __shared__ float sh[128];
    __shared__ float sh2[2];
    int b = blockIdx.x;            // t*KVH + kvh
    int t = b >> 2;
    int n = threadIdx.x;
    size_t base = (size_t)b * 128;
    float x = Kl[base + n];
    float ssq = block_sum_128(x * x, sh2);
    float kn = knw[n] * (x * rsqrtf(ssq * (1.f / 128.f) + 1e-6f));
    sh[n] = kn;
    __syncthreads();
    float rot = (n < 64) ? -sh[n + 64] : sh[n - 64];
    float c = cosT[(size_t)t * 128 + n], s = sinT[(size_t)t * 128 + n];
    float kr = kn * c + rot * s;
    float kf = kr + (kfirst[base + n] - kr) * kmix[base + n];
    float s2 = block_sum_128(kf * kf, sh2);
    float kkv = kf / fmaxf(sqrtf(s2), 1e-12f);
    float vv = Vl[base + n];
    float vf = vv + (vfirst[base + n] - vv) * vmix[base + n];
    Kl[base + n] = kf;
    kkO[base + n] = kkv;
    Vl[base + n] = vf;
}

// ---------------- prep for r / wdec / c (per (t,h)) ----------------
__global__ __launch_bounds__(128)
void prep_r(float* __restrict__ Rl,   // in: R_lin, out: r
            float* __restrict__ Wl,   // in: w_lin (+w0 bias), out: wdec
            const float* __restrict__ kfin,  // (T,KVH*N)
            const float* __restrict__ rk,    // (H,N)
            float* __restrict__ cOut,        // (T,H)
            const float* __restrict__ cosT, const float* __restrict__ sinT,
            const float* __restrict__ rnw) {
    __shared__ float sh[128];
    __shared__ float sh2[2];
    int b = blockIdx.x;            // t*H + h
    int t = b >> 4, h = b & 15;
    int kv = h >> 2;
    int n = threadIdx.x;
    size_t base = (size_t)b * 128;
    float x = Rl[base + n];
    float ssq = block_sum_128(x * x, sh2);
    float rn = rnw[n] * (x * rsqrtf(ssq * (1.f / 128.f) + 1e-6f));
    sh[n] = rn;
    __syncthreads();
    float rot = (n < 64) ? -sh[n + 64] : sh[n - 64];
    float c = cosT[(size_t)t * 128 + n], s = sinT[(size_t)t * 128 + n];
    float rr = rn * c + rot * s;
    Rl[base + n] = rr;
    // wdec = exp(-exp(-softplus(-z) - 0.5)), z already includes w0
    float z = Wl[base + n];
    float nz = -z;
    float sp = fmaxf(nz, 0.f) + log1pf(expf(-fabsf(nz)));
    float w = -sp - 0.5f;
    Wl[base + n] = expf(-expf(w));
    // c[t,h] = sum_n r*k_fin*r_k
    float pc = rr * kfin[((size_t)t * 4 + kv) * 128 + n] * rk[h * 128 + n];
    float cs = block_sum_128(pc, sh2);
    if (n == 0) cOut[b] = cs;
}

// ---------------- the sequential scan: one wave per (h, row i) ----------------
__global__ __launch_bounds__(256)
void scan_kernel(const float* __restrict__ wdec, const float* __restrict__ rA,
                 const float* __restrict__ aA, const float* __restrict__ kkA,
                 const float* __restrict__ kfA, const float* __restrict__ vfA,
                 float* __restrict__ y) {
    int gw = (blockIdx.x << 2) + (threadIdx.x >> 6);  // 0..2047
    int lane = threadIdx.x & 63;
    int h = gw >> 7, i = gw & 127, kv = h >> 2;
    const float2* wp = (const float2*)(wdec + h * 128) + lane;
    const float2* rp = (const float2*)(rA + h * 128) + lane;
    const float2* ap = (const float2*)(aA + h * 128) + lane;
    const float2* qp = (const float2*)(kkA + kv * 128) + lane;
    const float2* kp = (const float2*)(kfA + kv * 128) + lane;
    const float* vp = vfA + kv * 128 + i;
    float* yp = y + h * 128 + i;
    float S0 = 0.f, S1 = 0.f;
#pragma unroll 2
    for (int t = 0; t < T_; ++t) {
        float2 w2 = *wp; wp += 1024;   // stride H*N = 2048 floats
        float2 r2 = *rp; rp += 1024;
        float2 a2 = *ap; ap += 1024;
        float2 q2 = *qp; qp += 256;    // stride KVH*N = 512 floats
        float2 k2 = *kp; kp += 256;
        float vi = *vp;  vp += 512;
        // sa_i = sum_j S_ij * aa_j,  aa = -kk
        float p = S0 * q2.x + S1 * q2.y;
        float sa = -wave64_allsum(p);
        // S = S*w + sa*(kk*a) + v_i*k
        S0 = S0 * w2.x + sa * (q2.x * a2.x) + vi * k2.x;
        S1 = S1 * w2.y + sa * (q2.y * a2.y) + vi * k2.y;
        float yy = wave64_allsum(S0 * r2.x + S1 * r2.y);
        if (lane == 0) *yp = yy;
        yp += 2048;
    }
}

// ---------------- y -> bf16((y + c*v) * g) ----------------
__global__ void yg_kernel(const float* __restrict__ y, const float* __restrict__ cA,
                          const float* __restrict__ vf, const float* __restrict__ g,
                          __bf16* __restrict__ out) {
    int idx = blockIdx.x * 256 + threadIdx.x;  // T*2048 total
    int t = idx >> 11, col = idx & 2047;
    int h = col >> 7, n = col & 127, kv = h >> 2;
    float val = (y[idx] + cA[t * 16 + h] * vf[((size_t)t * 4 + kv) * 128 + n]) * g[idx];
    out[idx] = (__bf16)val;
}

// ---------------- orchestration ----------------
extern "C" void kernel_launch(void* const* d_in, const int* in_sizes, int n_in,
                              void* d_out, int out_size, void* d_ws, size_t ws_size,
                              hipStream_t stream) {
    (void)in_sizes; (void)n_in; (void)out_size; (void)ws_size;
    const float* x      = (const float*)d_in[0];
    const float* vfirst = (const float*)d_in[1];
    const float* kfirst = (const float*)d_in[2];
    const float* amask  = (const float*)d_in[3];
    const float* cosT   = (const float*)d_in[4];
    const float* sinT   = (const float*)d_in[5];
    const float* w0     = (const float*)d_in[6];
    const float* w1     = (const float*)d_in[7];
    const float* w2     = (const float*)d_in[8];
    const float* a0     = (const float*)d_in[9];
    const float* a1     = (const float*)d_in[10];
    const float* a2     = (const float*)d_in[11];
    const float* v0     = (const float*)d_in[12];
    const float* v1     = (const float*)d_in[13];
    const float* v2     = (const float*)d_in[14];
    const float* k0     = (const float*)d_in[15];
    const float* k1     = (const float*)d_in[16];
    const float* k2     = (const float*)d_in[17];
    const float* g1     = (const float*)d_in[18];
    const float* g2     = (const float*)d_in[19];
    const float* rk     = (const float*)d_in[20];
    const float* rnw    = (const float*)d_in[21];
    const float* knw    = (const float*)d_in[22];
    const float* W_r    = (const float*)d_in[23];
    const float* W_k    = (const float*)d_in[24];
    const float* W_v    = (const float*)d_in[25];
    const float* W_o    = (const float*)d_in[26];

    char* p = (char*)d_ws;
    auto take = [&](size_t bytes) { char* r = p; p += (bytes + 255) & ~(size_t)255; return r; };
    __bf16* wT  = (__bf16*)take((size_t)C_ * C_ * 2);   // transposed-weight arena (reused)
    __bf16* xmb = (__bf16*)take((size_t)T_ * C_ * 2);   // xm bf16; later reused for yg bf16
    float* Rl   = (float*)take((size_t)T_ * 2048 * 4);  // R_lin -> r
    float* Kl   = (float*)take((size_t)T_ * 512 * 4);   // K_lin -> k_fin
    float* Vl   = (float*)take((size_t)T_ * 512 * 4);   // V_lin -> v_fin
    float* kkB  = (float*)take((size_t)T_ * 512 * 4);   // kk
    float* Wl   = (float*)take((size_t)T_ * 2048 * 4);  // w_lin -> wdec
    float* aS   = (float*)take((size_t)T_ * 2048 * 4);  // a (sigmoid)
    float* vmx  = (float*)take((size_t)T_ * 512 * 4);
    float* kmx  = (float*)take((size_t)T_ * 512 * 4);
    float* gB   = (float*)take((size_t)T_ * 2048 * 4);
    __bf16* hS  = (__bf16*)take((size_t)T_ * 160 * 2);  // shared low-rank hidden
    float* cB   = (float*)take((size_t)T_ * H_ * 4);
    float* yB   = (float*)take((size_t)T_ * 2048 * 4);

    xm_to_bf16<<<(T_ * C_ / 4) / 256, 256, 0, stream>>>(x, amask, xmb);

    auto tr = [&](const float* src, int R, int C) {
        transpose_f32_bf16<<<dim3((C + 31) / 32, (R + 31) / 32), 256, 0, stream>>>(src, wT, R, C);
    };
    auto gemm = [&](const __bf16* A, int N, int K, const float* bias, float* Cf, __bf16* Cb, int act) {
        gemm_bf16_bt<<<dim3((N + 127) / 128, T_ / 128), 256, 0, stream>>>(A, wT, bias, Cf, Cb, N, K, act);
    };

    tr(W_r, 2048, 2048); gemm(xmb, 2048, 2048, nullptr, Rl, nullptr, 0);
    tr(W_k, 2048, 512);  gemm(xmb, 512, 2048, nullptr, Kl, nullptr, 0);
    tr(W_v, 2048, 512);  gemm(xmb, 512, 2048, nullptr, Vl, nullptr, 0);
    tr(w1, 2048, 160);   gemm(xmb, 160, 2048, nullptr, nullptr, hS, 1);   // tanh -> bf16
    tr(w2, 160, 2048);   gemm(hS, 2048, 160, w0, Wl, nullptr, 0);         // + w0
    tr(a1, 2048, 96);    gemm(xmb, 96, 2048, nullptr, nullptr, hS, 0);
    tr(a2, 96, 2048);    gemm(hS, 2048, 96, a0, aS, nullptr, 2);          // sigmoid
    tr(v1, 2048, 64);    gemm(xmb, 64, 2048, nullptr, nullptr, hS, 0);
    tr(v2, 64, 512);     gemm(hS, 512, 64, v0, vmx, nullptr, 2);
    tr(k1, 2048, 64);    gemm(xmb, 64, 2048, nullptr, nullptr, hS, 0);
    tr(k2, 64, 512);     gemm(hS, 512, 64, k0, kmx, nullptr, 2);
    tr(g1, 2048, 160);   gemm(xmb, 160, 2048, nullptr, nullptr, hS, 2);   // sigmoid -> bf16
    tr(g2, 160, 2048);   gemm(hS, 2048, 160, nullptr, gB, nullptr, 0);

    prep_kv<<<T_ * KVH_, 128, 0, stream>>>(Kl, Vl, kkB, kfirst, vfirst, kmx, vmx, cosT, sinT, knw);
    prep_r<<<T_ * H_, 128, 0, stream>>>(Rl, Wl, Kl, rk, cB, cosT, sinT, rnw);
    scan_kernel<<<512, 256, 0, stream>>>(Wl, Rl, aS, kkB, Kl, Vl, yB);
    yg_kernel<<<(T_ * 2048) / 256, 256, 0, stream>>>(yB, cB, Vl, gB, xmb);
    tr(W_o, 2048, 2048); gemm(xmb, 2048, 2048, nullptr, (float*)d_out, nullptr, 0);
}

// Round 2
// 1049.319 us; speedup vs baseline: 1.5181x; 1.5181x over previous
//
#include <hip/hip_runtime.h>
#include <hip/hip_bf16.h>
#include <math.h>

#define T_   2048
#define C_   2048
#define H_   16
#define N_   128
#define KVH_ 4

typedef __bf16 bf16x8 __attribute__((ext_vector_type(8)));
typedef __bf16 bf16x4 __attribute__((ext_vector_type(4)));
typedef float  f32x4  __attribute__((ext_vector_type(4)));

// ---------------- DPP wave64 all-reduce helpers ----------------
template <int CTRL>
static __device__ __forceinline__ float dppadd(float x) {
    int y = __builtin_amdgcn_update_dpp(0, __float_as_int(x), CTRL, 0xF, 0xF, true);
    return x + __int_as_float(y);
}
// three interleaved reductions (independent chains -> ILP). Full sums valid in lanes 48..63.
static __device__ __forceinline__ void red3(float& a, float& b, float& c) {
    a = dppadd<0xB1>(a);  b = dppadd<0xB1>(b);  c = dppadd<0xB1>(c);   // xor1
    a = dppadd<0x4E>(a);  b = dppadd<0x4E>(b);  c = dppadd<0x4E>(c);   // xor2
    a = dppadd<0x141>(a); b = dppadd<0x141>(b); c = dppadd<0x141>(c);  // half_mirror
    a = dppadd<0x140>(a); b = dppadd<0x140>(b); c = dppadd<0x140>(c);  // mirror
    a = dppadd<0x142>(a); b = dppadd<0x142>(b); c = dppadd<0x142>(c);  // bcast15
    a = dppadd<0x143>(a); b = dppadd<0x143>(b); c = dppadd<0x143>(c);  // bcast31
}

static __device__ __forceinline__ float wave_sum_shfl(float v) {
#pragma unroll
    for (int m = 32; m >= 1; m >>= 1) v += __shfl_xor(v, m, 64);
    return v;
}
static __device__ __forceinline__ float block_sum_128(float v, float* sh2) {
    v = wave_sum_shfl(v);
    if ((threadIdx.x & 63) == 0) sh2[threadIdx.x >> 6] = v;
    __syncthreads();
    float r = sh2[0] + sh2[1];
    __syncthreads();
    return r;
}

// ---------------- xm = bf16(x * mask) ----------------
__global__ void xm_to_bf16(const float* __restrict__ x, const float* __restrict__ mask,
                           __bf16* __restrict__ o) {
    int idx = blockIdx.x * 256 + threadIdx.x;
    int e = idx * 4;
    float4 v = *(const float4*)(x + e);
    float m = mask[e >> 11];
    bf16x4 r;
    r.x = (__bf16)(v.x * m); r.y = (__bf16)(v.y * m);
    r.z = (__bf16)(v.z * m); r.w = (__bf16)(v.w * m);
    *(bf16x4*)(o + e) = r;
}

// ---------------- batched tiled transpose f32 (R x C) -> bf16 (C x R) ----------------
struct TrDesc { const float* src; __bf16* dst; int R, C, tileStart; };
struct TrBatch { TrDesc d[13]; int n; };

__global__ void transpose_batch(TrBatch tb) {
    int bid = blockIdx.x;
    int e = 0;
    while (e + 1 < tb.n && tb.d[e + 1].tileStart <= bid) e++;
    const float* src = tb.d[e].src;
    __bf16* dst = tb.d[e].dst;
    int R = tb.d[e].R, C = tb.d[e].C;
    int tix = bid - tb.d[e].tileStart;
    int tilesC = (C + 31) >> 5;
    int trow = tix / tilesC, tcol = tix - trow * tilesC;
    int r0 = trow * 32, c0 = tcol * 32;
    __shared__ float tile[32][33];
    int tx = threadIdx.x & 31, ty = threadIdx.x >> 5;
#pragma unroll
    for (int i = 0; i < 4; i++) {
        int r = r0 + ty + i * 8, c = c0 + tx;
        if (r < R && c < C) tile[ty + i * 8][tx] = src[(size_t)r * C + c];
    }
    __syncthreads();
#pragma unroll
    for (int i = 0; i < 4; i++) {
        int c = c0 + ty + i * 8, r = r0 + tx;
        if (c < C && r < R) dst[(size_t)c * R + r] = (__bf16)tile[tx][ty + i * 8];
    }
}

__global__ void transpose_f32_bf16(const float* __restrict__ src, __bf16* __restrict__ dst,
                                   int R, int C) {
    __shared__ float tile[32][33];
    int tx = threadIdx.x & 31, ty = threadIdx.x >> 5;
    int c0 = blockIdx.x * 32, r0 = blockIdx.y * 32;
#pragma unroll
    for (int i = 0; i < 4; i++) {
        int r = r0 + ty + i * 8, c = c0 + tx;
        if (r < R && c < C) tile[ty + i * 8][tx] = src[(size_t)r * C + c];
    }
    __syncthreads();
#pragma unroll
    for (int i = 0; i < 4; i++) {
        int c = c0 + ty + i * 8, r = r0 + tx;
        if (c < C && r < R) dst[(size_t)c * R + r] = (__bf16)tile[tx][ty + i * 8];
    }
}

// ---------------- MFMA GEMM: C[M,N] = A[M,K] @ BT[N,K]^T ----------------
// MODE 0: f32 out (stride N), optional bias + act (0 none,1 tanh,2 sigmoid)
// MODE 2: mega split: col<3072 -> f32 (stride 3072); col>=3072 -> bf16 (stride 544)
//         with act tanh for [3072,3232), sigmoid for [3456,3616)
template <int MODE>
__global__ __launch_bounds__(256, 2)
void gemm_bf16(const __bf16* __restrict__ A, int lda, const __bf16* __restrict__ BT,
               const float* __restrict__ bias, float* __restrict__ Cf,
               __bf16* __restrict__ Cb, int N, int K, int act) {
    constexpr int LDK = 40;
    __shared__ __align__(16) __bf16 As[128 * LDK];
    __shared__ __align__(16) __bf16 Bs[128 * LDK];
    const int tid = threadIdx.x;
    const int lane = tid & 63, wave = tid >> 6;
    const int bm = blockIdx.y * 128, bn = blockIdx.x * 128;
    const int wm = (wave >> 1) * 64, wn = (wave & 1) * 64;
    const int srow = tid >> 1;
    const int skoff = (tid & 1) * 16;
    const __bf16* Ap = A + (size_t)(bm + srow) * lda + skoff;
    const __bf16* Bp = BT + (size_t)(bn + srow) * K + skoff;
    const bool bok = (bn + srow) < N;
    __bf16* AsW = As + srow * LDK + skoff;
    __bf16* BsW = Bs + srow * LDK + skoff;
    const int lm = lane & 15, lq = lane >> 4;
    f32x4 acc[4][4] = {};
    for (int k0 = 0; k0 < K; k0 += 32) {
        int4 a0 = *(const int4*)(Ap);
        int4 a1 = *(const int4*)(Ap + 8);
        int4 b0 = {0, 0, 0, 0}, b1 = {0, 0, 0, 0};
        if (bok) { b0 = *(const int4*)(Bp); b1 = *(const int4*)(Bp + 8); }
        __syncthreads();
        *(int4*)(AsW) = a0; *(int4*)(AsW + 8) = a1;
        *(int4*)(BsW) = b0; *(int4*)(BsW + 8) = b1;
        __syncthreads();
        bf16x8 af[4], bfr[4];
#pragma unroll
        for (int i = 0; i < 4; i++)
            af[i] = *(const bf16x8*)(As + (wm + i * 16 + lm) * LDK + lq * 8);
#pragma unroll
        for (int j = 0; j < 4; j++)
            bfr[j] = *(const bf16x8*)(Bs + (wn + j * 16 + lm) * LDK + lq * 8);
#pragma unroll
        for (int i = 0; i < 4; i++)
#pragma unroll
            for (int j = 0; j < 4; j++)
                acc[i][j] = __builtin_amdgcn_mfma_f32_16x16x32_bf16(af[i], bfr[j], acc[i][j], 0, 0, 0);
        Ap += 32; Bp += 32;
    }
#pragma unroll
    for (int j = 0; j < 4; j++) {
        int col = bn + wn + j * 16 + lm;
        if (col >= N) continue;
        float bv = (MODE == 0 && bias) ? bias[col] : 0.f;
#pragma unroll
        for (int i = 0; i < 4; i++) {
            int row0 = bm + wm + i * 16 + lq * 4;
#pragma unroll
            for (int rg = 0; rg < 4; rg++) {
                float v = acc[i][j][rg] + bv;
                int row = row0 + rg;
                if (MODE == 0) {
                    if (act == 1) v = tanhf(v);
                    else if (act == 2) v = 1.f / (1.f + __expf(-v));
                    Cf[(size_t)row * N + col] = v;
                } else {
                    if (col < 3072) {
                        Cf[(size_t)row * 3072 + col] = v;
                    } else {
                        float vv = v;
                        if (col < 3232) vv = tanhf(v);
                        else if (col >= 3456) vv = 1.f / (1.f + __expf(-v));
                        Cb[(size_t)row * 544 + (col - 3072)] = (__bf16)vv;
                    }
                }
            }
        }
    }
}

// ---------------- prep for k/v (per (t,kvh)); mega row stride 3072 ----------------
__global__ __launch_bounds__(128)
void prep_kv(float* __restrict__ mega, float* __restrict__ kkO,
             const float* __restrict__ kfirst, const float* __restrict__ vfirst,
             const float* __restrict__ kmix, const float* __restrict__ vmix,
             const float* __restrict__ cosT, const float* __restrict__ sinT,
             const float* __restrict__ knw) {
    __shared__ float sh[128];
    __shared__ float sh2[2];
    int b = blockIdx.x;
    int t = b >> 2, kvh = b & 3;
    int n = threadIdx.x;
    size_t kbase = (size_t)t * 3072 + 2048 + kvh * 128;
    size_t vbase = (size_t)t * 3072 + 2560 + kvh * 128;
    size_t fbase = (size_t)t * 512 + kvh * 128;
    float x = mega[kbase + n];
    float ssq = block_sum_128(x * x, sh2);
    float kn = knw[n] * (x * rsqrtf(ssq * (1.f / 128.f) + 1e-6f));
    sh[n] = kn;
    __syncthreads();
    float rot = (n < 64) ? -sh[n + 64] : sh[n - 64];
    float c = cosT[(size_t)t * 128 + n], s = sinT[(size_t)t * 128 + n];
    float kr = kn * c + rot * s;
    float kf = kr + (kfirst[fbase + n] - kr) * kmix[fbase + n];
    float s2 = block_sum_128(kf * kf, sh2);
    float kkv = kf / fmaxf(sqrtf(s2), 1e-12f);
    float vv = mega[vbase + n];
    float vf = vv + (vfirst[fbase + n] - vv) * vmix[fbase + n];
    mega[kbase + n] = kf;
    kkO[fbase + n] = kkv;
    mega[vbase + n] = vf;
}

// ---------------- prep for r / wdec / c (per (t,h)) ----------------
__global__ __launch_bounds__(128)
void prep_r(float* __restrict__ mega, float* __restrict__ Wl,
            const float* __restrict__ rk, float* __restrict__ cOut,
            const float* __restrict__ cosT, const float* __restrict__ sinT,
            const float* __restrict__ rnw) {
    __shared__ float sh[128];
    __shared__ float sh2[2];
    int b = blockIdx.x;
    int t = b >> 4, h = b & 15;
    int kv = h >> 2;
    int n = threadIdx.x;
    size_t rbase = (size_t)t * 3072 + h * 128;
    float x = mega[rbase + n];
    float ssq = block_sum_128(x * x, sh2);
    float rn = rnw[n] * (x * rsqrtf(ssq * (1.f / 128.f) + 1e-6f));
    sh[n] = rn;
    __syncthreads();
    float rot = (n < 64) ? -sh[n + 64] : sh[n - 64];
    float c = cosT[(size_t)t * 128 + n], s = sinT[(size_t)t * 128 + n];
    float rr = rn * c + rot * s;
    mega[rbase + n] = rr;
    size_t wb_ = (size_t)t * 2048 + h * 128 + n;
    float z = Wl[wb_];
    float nz = -z;
    float sp = fmaxf(nz, 0.f) + log1pf(expf(-fabsf(nz)));
    float w = -sp - 0.5f;
    Wl[wb_] = expf(-expf(w));
    float pc = rr * mega[(size_t)t * 3072 + 2048 + kv * 128 + n] * rk[h * 128 + n];
    float cs = block_sum_128(pc, sh2);
    if (n == 0) cOut[b] = cs;
}

// ---------------- the sequential scan: one wave per (h, row i) ----------------
// streams: wdec (T x 2048), mega (T x 3072: r|k|v), aA (T x 2048), kkA (T x 512)
// depth-4 register prefetch; 3 independent DPP reductions per step.
__global__ __launch_bounds__(256)
void scan_kernel(const float* __restrict__ wdec, const float* __restrict__ mega,
                 const float* __restrict__ aA, const float* __restrict__ kkA,
                 float* __restrict__ y) {
    int gw = (blockIdx.x << 2) + (threadIdx.x >> 6);
    int lane = threadIdx.x & 63;
    int h = gw >> 7, i = gw & 127, kv = h >> 2;
    const float2* wp = (const float2*)(wdec + h * 128) + lane;
    const float2* rp = (const float2*)(mega + h * 128) + lane;
    const float2* ap = (const float2*)(aA + h * 128) + lane;
    const float2* qp = (const float2*)(kkA + kv * 128) + lane;
    const float2* kp = (const float2*)(mega + 2048 + kv * 128) + lane;
    const float*  vp = mega + 2560 + kv * 128 + i;
    float* yp = y + h * 128 + i;
    constexpr int PF = 4;
    float2 wb[PF], rb[PF], ab[PF], qb[PF], kb[PF]; float vb[PF];
#pragma unroll
    for (int j = 0; j < PF; ++j) {
        wb[j] = wp[0]; wp += 1024;
        rb[j] = rp[0]; rp += 1536;
        ab[j] = ap[0]; ap += 1024;
        qb[j] = qp[0]; qp += 256;
        kb[j] = kp[0]; kp += 1536;
        vb[j] = vp[0]; vp += 3072;
    }
    float S0 = 0.f, S1 = 0.f;
#pragma unroll 4
    for (int t = 0; t < T_; ++t) {
        int j = t & 3;
        float2 w2 = wb[j], r2 = rb[j], a2 = ab[j], q2 = qb[j], k2 = kb[j];
        float vi = vb[j];
        // prefetch t+PF (over-reads last 4 rows into following ws buffers: harmless)
        wb[j] = wp[0]; wp += 1024;
        rb[j] = rp[0]; rp += 1536;
        ab[j] = ap[0]; ap += 1024;
        qb[j] = qp[0]; qp += 256;
        kb[j] = kp[0]; kp += 1536;
        vb[j] = vp[0]; vp += 3072;
        float t0 = S0 * w2.x, t1 = S1 * w2.y;
        float u0 = fmaf(vi, k2.x, t0), u1 = fmaf(vi, k2.y, t1);
        float p  = fmaf(S0, q2.x, S1 * q2.y);          // -> sa (critical path)
        float qa0 = q2.x * a2.x, qa1 = q2.y * a2.y;
        float z  = fmaf(u0, r2.x, u1 * r2.y);          // y part 1
        float pq = fmaf(qa0, r2.x, qa1 * r2.y);        // y part 2 coeff
        red3(p, z, pq);                                 // 3 independent chains
        float sa = -__int_as_float(__builtin_amdgcn_readlane(__float_as_int(p), 63));
        S0 = fmaf(sa, qa0, u0);
        S1 = fmaf(sa, qa1, u1);
        float yv = fmaf(sa, pq, z);                     // valid in lanes 48..63
        if (lane == 63) yp[t * 2048] = yv;
    }
}

// ---------------- y -> bf16((y + c*v) * g) ----------------
__global__ void yg_kernel(const float* __restrict__ y, const float* __restrict__ cA,
                          const float* __restrict__ mega, const float* __restrict__ g,
                          __bf16* __restrict__ out) {
    int idx = blockIdx.x * 256 + threadIdx.x;
    int t = idx >> 11, col = idx & 2047;
    int h = col >> 7, n = col & 127, kv = h >> 2;
    float vf = mega[(size_t)t * 3072 + 2560 + kv * 128 + n];
    float val = (y[idx] + cA[t * 16 + h] * vf) * g[idx];
    out[idx] = (__bf16)val;
}

// ---------------- orchestration ----------------
extern "C" void kernel_launch(void* const* d_in, const int* in_sizes, int n_in,
                              void* d_out, int out_size, void* d_ws, size_t ws_size,
                              hipStream_t stream) {
    (void)in_sizes; (void)n_in; (void)out_size; (void)ws_size;
    const float* x      = (const float*)d_in[0];
    const float* vfirst = (const float*)d_in[1];
    const float* kfirst = (const float*)d_in[2];
    const float* amask  = (const float*)d_in[3];
    const float* cosT   = (const float*)d_in[4];
    const float* sinT   = (const float*)d_in[5];
    const float* w0     = (const float*)d_in[6];
    const float* w1     = (const float*)d_in[7];
    const float* w2     = (const float*)d_in[8];
    const float* a0     = (const float*)d_in[9];
    const float* a1     = (const float*)d_in[10];
    const float* a2     = (const float*)d_in[11];
    const float* v0     = (const float*)d_in[12];
    const float* v1     = (const float*)d_in[13];
    const float* v2     = (const float*)d_in[14];
    const float* k0     = (const float*)d_in[15];
    const float* k1     = (const float*)d_in[16];
    const float* k2     = (const float*)d_in[17];
    const float* g1     = (const float*)d_in[18];
    const float* g2     = (const float*)d_in[19];
    const float* rk     = (const float*)d_in[20];
    const float* rnw    = (const float*)d_in[21];
    const float* knw    = (const float*)d_in[22];
    const float* W_r    = (const float*)d_in[23];
    const float* W_k    = (const float*)d_in[24];
    const float* W_v    = (const float*)d_in[25];
    const float* W_o    = (const float*)d_in[26];

    char* p = (char*)d_ws;
    auto take = [&](size_t bytes) { char* r = p; p += (bytes + 255) & ~(size_t)255; return r; };
    __bf16* arena   = (__bf16*)take((size_t)3616 * 2048 * 2);  // x-side BT; later reused for W_o^T
    __bf16* xmb     = (__bf16*)take((size_t)T_ * C_ * 2);      // xm bf16; reused for yg bf16
    float*  megaF   = (float*)take((size_t)T_ * 3072 * 4);     // r | k | v  (f32, stride 3072)
    __bf16* megaB   = (__bf16*)take((size_t)T_ * 544 * 2);     // hiddens bf16, stride 544
    __bf16* w2T     = (__bf16*)take((size_t)2048 * 160 * 2);
    __bf16* a2T     = (__bf16*)take((size_t)2048 * 96 * 2);
    __bf16* v2T     = (__bf16*)take((size_t)512 * 64 * 2);
    __bf16* k2T     = (__bf16*)take((size_t)512 * 64 * 2);
    __bf16* g2T     = (__bf16*)take((size_t)2048 * 160 * 2);
    float*  Wl      = (float*)take((size_t)T_ * 2048 * 4);     // w_lin -> wdec
    float*  aS      = (float*)take((size_t)T_ * 2048 * 4);     // a
    float*  gB      = (float*)take((size_t)T_ * 2048 * 4);     // g
    float*  kkB     = (float*)take((size_t)T_ * 512 * 4);      // kk
    float*  vmx     = (float*)take((size_t)T_ * 512 * 4);
    float*  kmx     = (float*)take((size_t)T_ * 512 * 4);
    float*  yB      = (float*)take((size_t)T_ * 2048 * 4);
    float*  cB      = (float*)take((size_t)T_ * H_ * 4);

    xm_to_bf16<<<(T_ * C_ / 4) / 256, 256, 0, stream>>>(x, amask, xmb);

    // batched transpose of all weights except W_o
    TrBatch tb;
    {
        const float* srcs[13] = {W_r, W_k, W_v, w1, a1, v1, k1, g1, w2, a2, v2, k2, g2};
        __bf16* dsts[13] = {arena, arena + (size_t)2048 * 2048, arena + (size_t)2560 * 2048,
                            arena + (size_t)3072 * 2048, arena + (size_t)3232 * 2048,
                            arena + (size_t)3328 * 2048, arena + (size_t)3392 * 2048,
                            arena + (size_t)3456 * 2048, w2T, a2T, v2T, k2T, g2T};
        int Rs[13] = {2048, 2048, 2048, 2048, 2048, 2048, 2048, 2048, 160, 96, 64, 64, 160};
        int Cs[13] = {2048, 512, 512, 160, 96, 64, 64, 160, 2048, 2048, 512, 512, 2048};
        int cum = 0;
        for (int e = 0; e < 13; e++) {
            tb.d[e].src = srcs[e]; tb.d[e].dst = dsts[e];
            tb.d[e].R = Rs[e]; tb.d[e].C = Cs[e]; tb.d[e].tileStart = cum;
            cum += ((Rs[e] + 31) / 32) * ((Cs[e] + 31) / 32);
        }
        tb.n = 13;
        transpose_batch<<<cum, 256, 0, stream>>>(tb);
    }

    // mega GEMM: all 8 x-side projections in one launch (N=3616, K=2048)
    gemm_bf16<2><<<dim3(29, 16), 256, 0, stream>>>(xmb, 2048, arena, nullptr, megaF, megaB, 3616, 2048, 0);

    // down projections from bf16 hidden (lda=544)
    gemm_bf16<0><<<dim3(16, 16), 256, 0, stream>>>(megaB + 0,   544, w2T, w0, Wl,  nullptr, 2048, 160, 0);
    gemm_bf16<0><<<dim3(16, 16), 256, 0, stream>>>(megaB + 160, 544, a2T, a0, aS,  nullptr, 2048, 96, 2);
    gemm_bf16<0><<<dim3(4, 16),  256, 0, stream>>>(megaB + 256, 544, v2T, v0, vmx, nullptr, 512, 64, 2);
    gemm_bf16<0><<<dim3(4, 16),  256, 0, stream>>>(megaB + 320, 544, k2T, k0, kmx, nullptr, 512, 64, 2);
    gemm_bf16<0><<<dim3(16, 16), 256, 0, stream>>>(megaB + 384, 544, g2T, nullptr, gB, nullptr, 2048, 160, 0);

    prep_kv<<<T_ * KVH_, 128, 0, stream>>>(megaF, kkB, kfirst, vfirst, kmx, vmx, cosT, sinT, knw);
    prep_r<<<T_ * H_, 128, 0, stream>>>(megaF, Wl, rk, cB, cosT, sinT, rnw);
    scan_kernel<<<512, 256, 0, stream>>>(Wl, megaF, aS, kkB, yB);
    yg_kernel<<<(T_ * 2048) / 256, 256, 0, stream>>>(yB, cB, megaF, gB, xmb);

    // W_o^T into (now free) arena, then final GEMM -> d_out (f32)
    transpose_f32_bf16<<<dim3(64, 64), 256, 0, stream>>>(W_o, arena, 2048, 2048);
    gemm_bf16<0><<<dim3(16, 16), 256, 0, stream>>>(xmb, 2048, arena, nullptr, (float*)d_out, nullptr, 2048, 2048, 0);
}

// Round 3
// 957.057 us; speedup vs baseline: 1.6645x; 1.0964x over previous
//
#include <hip/hip_runtime.h>
#include <hip/hip_bf16.h>
#include <math.h>

#define T_   2048
#define C_   2048
#define H_   16
#define N_   128
#define KVH_ 4

typedef __bf16 bf16x8 __attribute__((ext_vector_type(8)));
typedef __bf16 bf16x4 __attribute__((ext_vector_type(4)));
typedef float  f32x4  __attribute__((ext_vector_type(4)));

#define MFMA16(a, b, c) __builtin_amdgcn_mfma_f32_16x16x32_bf16(a, b, c, 0, 0, 0)

static __device__ __forceinline__ float wave_sum_shfl(float v) {
#pragma unroll
    for (int m = 32; m >= 1; m >>= 1) v += __shfl_xor(v, m, 64);
    return v;
}
static __device__ __forceinline__ float block_sum_128(float v, float* sh2) {
    v = wave_sum_shfl(v);
    if ((threadIdx.x & 63) == 0) sh2[threadIdx.x >> 6] = v;
    __syncthreads();
    float r = sh2[0] + sh2[1];
    __syncthreads();
    return r;
}

// ---------------- xm = bf16(x * mask) ----------------
__global__ void xm_to_bf16(const float* __restrict__ x, const float* __restrict__ mask,
                           __bf16* __restrict__ o) {
    int idx = blockIdx.x * 256 + threadIdx.x;
    int e = idx * 4;
    float4 v = *(const float4*)(x + e);
    float m = mask[e >> 11];
    bf16x4 r;
    r.x = (__bf16)(v.x * m); r.y = (__bf16)(v.y * m);
    r.z = (__bf16)(v.z * m); r.w = (__bf16)(v.w * m);
    *(bf16x4*)(o + e) = r;
}

// ---------------- batched tiled transpose f32 (R x C) -> bf16 (C x R) ----------------
struct TrDesc { const float* src; __bf16* dst; int R, C, tileStart; };
struct TrBatch { TrDesc d[13]; int n; };

__global__ void transpose_batch(TrBatch tb) {
    int bid = blockIdx.x;
    int e = 0;
    while (e + 1 < tb.n && tb.d[e + 1].tileStart <= bid) e++;
    const float* src = tb.d[e].src;
    __bf16* dst = tb.d[e].dst;
    int R = tb.d[e].R, C = tb.d[e].C;
    int tix = bid - tb.d[e].tileStart;
    int tilesC = (C + 31) >> 5;
    int trow = tix / tilesC, tcol = tix - trow * tilesC;
    int r0 = trow * 32, c0 = tcol * 32;
    __shared__ float tile[32][33];
    int tx = threadIdx.x & 31, ty = threadIdx.x >> 5;
#pragma unroll
    for (int i = 0; i < 4; i++) {
        int r = r0 + ty + i * 8, c = c0 + tx;
        if (r < R && c < C) tile[ty + i * 8][tx] = src[(size_t)r * C + c];
    }
    __syncthreads();
#pragma unroll
    for (int i = 0; i < 4; i++) {
        int c = c0 + ty + i * 8, r = r0 + tx;
        if (c < C && r < R) dst[(size_t)c * R + r] = (__bf16)tile[tx][ty + i * 8];
    }
}

__global__ void transpose_f32_bf16(const float* __restrict__ src, __bf16* __restrict__ dst,
                                   int R, int C) {
    __shared__ float tile[32][33];
    int tx = threadIdx.x & 31, ty = threadIdx.x >> 5;
    int c0 = blockIdx.x * 32, r0 = blockIdx.y * 32;
#pragma unroll
    for (int i = 0; i < 4; i++) {
        int r = r0 + ty + i * 8, c = c0 + tx;
        if (r < R && c < C) tile[ty + i * 8][tx] = src[(size_t)r * C + c];
    }
    __syncthreads();
#pragma unroll
    for (int i = 0; i < 4; i++) {
        int c = c0 + ty + i * 8, r = r0 + tx;
        if (c < C && r < R) dst[(size_t)c * R + r] = (__bf16)tile[tx][ty + i * 8];
    }
}

// ---------------- MFMA GEMM: C[M,N] = A[M,K] @ BT[N,K]^T ----------------
template <int MODE>
__global__ __launch_bounds__(256, 2)
void gemm_bf16(const __bf16* __restrict__ A, int lda, const __bf16* __restrict__ BT,
               const float* __restrict__ bias, float* __restrict__ Cf,
               __bf16* __restrict__ Cb, int N, int K, int act) {
    constexpr int LDK = 40;
    __shared__ __align__(16) __bf16 As[128 * LDK];
    __shared__ __align__(16) __bf16 Bs[128 * LDK];
    const int tid = threadIdx.x;
    const int lane = tid & 63, wave = tid >> 6;
    const int bm = blockIdx.y * 128, bn = blockIdx.x * 128;
    const int wm = (wave >> 1) * 64, wn = (wave & 1) * 64;
    const int srow = tid >> 1;
    const int skoff = (tid & 1) * 16;
    const __bf16* Ap = A + (size_t)(bm + srow) * lda + skoff;
    const __bf16* Bp = BT + (size_t)(bn + srow) * K + skoff;
    const bool bok = (bn + srow) < N;
    __bf16* AsW = As + srow * LDK + skoff;
    __bf16* BsW = Bs + srow * LDK + skoff;
    const int lm = lane & 15, lq = lane >> 4;
    f32x4 acc[4][4] = {};
    for (int k0 = 0; k0 < K; k0 += 32) {
        int4 a0 = *(const int4*)(Ap);
        int4 a1 = *(const int4*)(Ap + 8);
        int4 b0 = {0, 0, 0, 0}, b1 = {0, 0, 0, 0};
        if (bok) { b0 = *(const int4*)(Bp); b1 = *(const int4*)(Bp + 8); }
        __syncthreads();
        *(int4*)(AsW) = a0; *(int4*)(AsW + 8) = a1;
        *(int4*)(BsW) = b0; *(int4*)(BsW + 8) = b1;
        __syncthreads();
        bf16x8 af[4], bfr[4];
#pragma unroll
        for (int i = 0; i < 4; i++)
            af[i] = *(const bf16x8*)(As + (wm + i * 16 + lm) * LDK + lq * 8);
#pragma unroll
        for (int j = 0; j < 4; j++)
            bfr[j] = *(const bf16x8*)(Bs + (wn + j * 16 + lm) * LDK + lq * 8);
#pragma unroll
        for (int i = 0; i < 4; i++)
#pragma unroll
            for (int j = 0; j < 4; j++)
                acc[i][j] = MFMA16(af[i], bfr[j], acc[i][j]);
        Ap += 32; Bp += 32;
    }
#pragma unroll
    for (int j = 0; j < 4; j++) {
        int col = bn + wn + j * 16 + lm;
        if (col >= N) continue;
        float bv = (MODE == 0 && bias) ? bias[col] : 0.f;
#pragma unroll
        for (int i = 0; i < 4; i++) {
            int row0 = bm + wm + i * 16 + lq * 4;
#pragma unroll
            for (int rg = 0; rg < 4; rg++) {
                float v = acc[i][j][rg] + bv;
                int row = row0 + rg;
                if (MODE == 0) {
                    if (act == 1) v = tanhf(v);
                    else if (act == 2) v = 1.f / (1.f + __expf(-v));
                    Cf[(size_t)row * N + col] = v;
                } else {
                    if (col < 3072) {
                        Cf[(size_t)row * 3072 + col] = v;
                    } else {
                        float vv = v;
                        if (col < 3232) vv = tanhf(v);
                        else if (col >= 3456) vv = 1.f / (1.f + __expf(-v));
                        Cb[(size_t)row * 544 + (col - 3072)] = (__bf16)vv;
                    }
                }
            }
        }
    }
}

// ---------------- prep for k/v (per (t,kvh)); mega row stride 3072 ----------------
__global__ __launch_bounds__(128)
void prep_kv(float* __restrict__ mega, float* __restrict__ kkO,
             const float* __restrict__ kfirst, const float* __restrict__ vfirst,
             const float* __restrict__ kmix, const float* __restrict__ vmix,
             const float* __restrict__ cosT, const float* __restrict__ sinT,
             const float* __restrict__ knw) {
    __shared__ float sh[128];
    __shared__ float sh2[2];
    int b = blockIdx.x;
    int t = b >> 2, kvh = b & 3;
    int n = threadIdx.x;
    size_t kbase = (size_t)t * 3072 + 2048 + kvh * 128;
    size_t vbase = (size_t)t * 3072 + 2560 + kvh * 128;
    size_t fbase = (size_t)t * 512 + kvh * 128;
    float x = mega[kbase + n];
    float ssq = block_sum_128(x * x, sh2);
    float kn = knw[n] * (x * rsqrtf(ssq * (1.f / 128.f) + 1e-6f));
    sh[n] = kn;
    __syncthreads();
    float rot = (n < 64) ? -sh[n + 64] : sh[n - 64];
    float c = cosT[(size_t)t * 128 + n], s = sinT[(size_t)t * 128 + n];
    float kr = kn * c + rot * s;
    float kf = kr + (kfirst[fbase + n] - kr) * kmix[fbase + n];
    float s2 = block_sum_128(kf * kf, sh2);
    float kkv = kf / fmaxf(sqrtf(s2), 1e-12f);
    float vv = mega[vbase + n];
    float vf = vv + (vfirst[fbase + n] - vv) * vmix[fbase + n];
    mega[kbase + n] = kf;
    kkO[fbase + n] = kkv;
    mega[vbase + n] = vf;
}

// ---------------- prep for r / wdec / c (per (t,h)) ----------------
__global__ __launch_bounds__(128)
void prep_r(float* __restrict__ mega, float* __restrict__ Wl,
            const float* __restrict__ rk, float* __restrict__ cOut,
            const float* __restrict__ cosT, const float* __restrict__ sinT,
            const float* __restrict__ rnw) {
    __shared__ float sh[128];
    __shared__ float sh2[2];
    int b = blockIdx.x;
    int t = b >> 4, h = b & 15;
    int kv = h >> 2;
    int n = threadIdx.x;
    size_t rbase = (size_t)t * 3072 + h * 128;
    float x = mega[rbase + n];
    float ssq = block_sum_128(x * x, sh2);
    float rn = rnw[n] * (x * rsqrtf(ssq * (1.f / 128.f) + 1e-6f));
    sh[n] = rn;
    __syncthreads();
    float rot = (n < 64) ? -sh[n + 64] : sh[n - 64];
    float c = cosT[(size_t)t * 128 + n], s = sinT[(size_t)t * 128 + n];
    float rr = rn * c + rot * s;
    mega[rbase + n] = rr;
    size_t wb_ = (size_t)t * 2048 + h * 128 + n;
    float z = Wl[wb_];
    float nz = -z;
    float sp = fmaxf(nz, 0.f) + log1pf(expf(-fabsf(nz)));
    float w = -sp - 0.5f;
    Wl[wb_] = expf(-expf(w));
    float pc = rr * mega[(size_t)t * 3072 + 2048 + kv * 128 + n] * rk[h * 128 + n];
    float cs = block_sum_128(pc, sh2);
    if (n == 0) cOut[b] = cs;
}

// =====================================================================
// Chunked scan, L=32 per chunk, 64 chunks. WY/UT transform:
//  S_t = S_{t-1} diag(w_t) + (S_{t-1} aa_t) bb_t^T + v_t k_t^T, y_t = S_t r_t
//  cw_t = prod_{s<=t} w_s ; A~_t = cw_{t-1}*aa_t ; B^_t = bb_t/cw_t ;
//  K^_t = k_t/cw_t ; R^_t = cw_t*r_t ; M[s][t]=B^_s.A~_t (s<t);
//  P[s][t]=K^_s.A~_t (s<t); T=(I-M)^{-1}; C = S0*(A~T) + V*(P T);
//  Y = S0*R^ + C*Gb + V*Gk (G masked s<=t); S_L = (S0 + C B^T + V K^T)*cw_L
// =====================================================================

// ---- phase A: per (head, chunk) = 1024 blocks x 1 wave -------------
__global__ __launch_bounds__(64)
void scan_phaseA(const float* __restrict__ Wl, const float* __restrict__ megaF,
                 const float* __restrict__ aS, const float* __restrict__ kkB,
                 __bf16* __restrict__ ATt_g, __bf16* __restrict__ Rr_g,
                 __bf16* __restrict__ Bnt_g, __bf16* __restrict__ Knt_g,
                 __bf16* __restrict__ Vt_g, __bf16* __restrict__ Gbt_g,
                 __bf16* __restrict__ Gkt_g, float* __restrict__ Cloc_g,
                 float* __restrict__ cwL_g) {
    __shared__ __align__(16) __bf16 pool[27648];
    __bf16* Arm = pool;            // [32][136]  A~ row-major
    __bf16* Brm = pool + 4352;     // [32][136]  B^
    __bf16* Krm = pool + 8704;     // [32][136]  K^
    __bf16* Rrm = pool + 13056;    // [32][136]  R^
    __bf16* Vt  = pool + 17408;    // [128][40]  V [i][t]
    __bf16* Mrm = pool + 22528;    // [32][40]
    __bf16* Mt  = pool + 23808;    // [32][40]
    __bf16* Prm = pool + 25088;    // [32][40]
    __bf16* Gtmp= pool + 26368;    // [32][40]
    // phase-2 region overlaps Brm/Krm/Rrm (freed after copies):
    __bf16* M2rm = pool + 4352;
    __bf16* M2t  = pool + 5632;
    __bf16* Xa   = pool + 6912;
    __bf16* Xb   = pool + 8192;
    __bf16* Tt   = pool + 9472;    // [t'][s] = T[s][t']
    __bf16* PTt  = pool + 10752;   // [t'][s] = (P*T)[s][t']

    const int l = threadIdx.x, lm = l & 15, lq = l >> 4;
    const int u = blockIdx.x, h = u >> 6, c = u & 63, kv = h >> 2;
    const int n0 = l, n1 = l + 64;

    float cw0 = 1.f, cw1 = 1.f;
    for (int t = 0; t < 32; ++t) {
        int tg = c * 32 + t;
        size_t hb = (size_t)tg * 2048 + h * 128;
        size_t mb = (size_t)tg * 3072;
        size_t kb = (size_t)tg * 512 + kv * 128;
        float wv0 = Wl[hb + n0], wv1 = Wl[hb + n1];
        float r0 = megaF[mb + h * 128 + n0], r1 = megaF[mb + h * 128 + n1];
        float q0 = kkB[kb + n0], q1 = kkB[kb + n1];
        float s0 = aS[hb + n0], s1 = aS[hb + n1];
        float k0 = megaF[mb + 2048 + kv * 128 + n0], k1 = megaF[mb + 2048 + kv * 128 + n1];
        float v0 = megaF[mb + 2560 + kv * 128 + n0], v1 = megaF[mb + 2560 + kv * 128 + n1];
        float cp0 = cw0, cp1 = cw1;
        cw0 *= wv0; cw1 *= wv1;
        float ic0 = 1.f / cw0, ic1 = 1.f / cw1;
        Arm[t * 136 + n0] = (__bf16)(-cp0 * q0);
        Arm[t * 136 + n1] = (__bf16)(-cp1 * q1);
        Brm[t * 136 + n0] = (__bf16)(q0 * s0 * ic0);
        Brm[t * 136 + n1] = (__bf16)(q1 * s1 * ic1);
        Krm[t * 136 + n0] = (__bf16)(k0 * ic0);
        Krm[t * 136 + n1] = (__bf16)(k1 * ic1);
        Rrm[t * 136 + n0] = (__bf16)(cw0 * r0);
        Rrm[t * 136 + n1] = (__bf16)(cw1 * r1);
        Vt[n0 * 40 + t] = (__bf16)v0;
        Vt[n1 * 40 + t] = (__bf16)v1;
    }
    cwL_g[(size_t)u * 128 + n0] = cw0;
    cwL_g[(size_t)u * 128 + n1] = cw1;
    __syncthreads();

    // D[r][c] = sum_n Ao[r][n]*Bo[c][n]; masked write (dTr transposed, dDir direct)
    auto mmLL = [&](const __bf16* Ao, const __bf16* Bo, bool incl, __bf16* dTr, __bf16* dDir) {
#pragma unroll
        for (int ri = 0; ri < 2; ri++)
#pragma unroll
        for (int ci = 0; ci < 2; ci++) {
            f32x4 acc = {};
#pragma unroll
            for (int s = 0; s < 4; s++) {
                bf16x8 af = *(const bf16x8*)(Ao + (ri * 16 + lm) * 136 + s * 32 + lq * 8);
                bf16x8 bf = *(const bf16x8*)(Bo + (ci * 16 + lm) * 136 + s * 32 + lq * 8);
                acc = MFMA16(af, bf, acc);
            }
#pragma unroll
            for (int rg = 0; rg < 4; rg++) {
                int rr = ri * 16 + lq * 4 + rg, cc = ci * 16 + lm;
                bool keep = incl ? (cc <= rr) : (cc < rr);
                __bf16 bv = (__bf16)(keep ? acc[rg] : 0.f);
                if (dTr)  dTr[cc * 40 + rr] = bv;
                if (dDir) dDir[rr * 40 + cc] = bv;
            }
        }
    };
    // D[t][s]=A~_t.B^_s = M[s][t]  (keep s<t)
    mmLL(Arm, Brm, false, Mrm, Mt);
    // D[t][s]=A~_t.K^_s = P[s][t]  (keep s<t)
    mmLL(Arm, Krm, false, Prm, nullptr);
    // D[t][s]=R^_t.B^_s = Gb[s][t] -> direct == Gbt[t][s]  (keep s<=t)
    mmLL(Rrm, Brm, true, nullptr, Gtmp);
    __syncthreads();
    for (int i = l; i < 512; i += 64) {
        int r = i >> 4, cp = i & 15;
        ((int*)(Gbt_g + (size_t)u * 1024))[i] = *(const int*)(Gtmp + r * 40 + cp * 2);
    }
    __syncthreads();
    mmLL(Rrm, Krm, true, nullptr, Gtmp);
    __syncthreads();
    for (int i = l; i < 512; i += 64) {
        int r = i >> 4, cp = i & 15;
        ((int*)(Gkt_g + (size_t)u * 1024))[i] = *(const int*)(Gtmp + r * 40 + cp * 2);
    }
    // R^ out [32][128]
    for (int i = l; i < 2048; i += 64) {
        int t = i >> 6, cp = i & 63;
        ((int*)(Rr_g + (size_t)u * 4096))[i] = *(const int*)(Rrm + t * 136 + cp * 2);
    }
    // B^/K^ transposed out [n][32]
    for (int i = l; i < 2048; i += 64) {
        int n = i >> 4, tp = i & 15;
        unsigned int lo = ((const unsigned short*)Brm)[(2 * tp) * 136 + n];
        unsigned int hi = ((const unsigned short*)Brm)[(2 * tp + 1) * 136 + n];
        ((unsigned int*)(Bnt_g + (size_t)u * 4096))[i] = lo | (hi << 16);
        unsigned int lo2 = ((const unsigned short*)Krm)[(2 * tp) * 136 + n];
        unsigned int hi2 = ((const unsigned short*)Krm)[(2 * tp + 1) * 136 + n];
        ((unsigned int*)(Knt_g + (size_t)u * 4096))[i] = lo2 | (hi2 << 16);
    }
    // V out [i][32]
    for (int i = l; i < 2048; i += 64) {
        int n = i >> 4, tp = i & 15;
        ((int*)(Vt_g + (size_t)u * 4096))[i] = *(const int*)(Vt + n * 40 + tp * 2);
    }
    __syncthreads();

    // Xa = I + M
    for (int i = l; i < 1024; i += 64) {
        int s = i >> 5, t = i & 31;
        Xa[s * 40 + t] = (s == t) ? (__bf16)1.f : Mrm[s * 40 + t];
    }
    __syncthreads();

    // D[r][c] = (accIn[r][c]) + sum_k Ao[r][k]*Bo[c][k]
    auto mat32 = [&](const __bf16* Ao, const __bf16* Bo, const __bf16* accIn,
                     __bf16* oRm, __bf16* oT) {
#pragma unroll
        for (int ri = 0; ri < 2; ri++)
#pragma unroll
        for (int ci = 0; ci < 2; ci++) {
            f32x4 acc = {};
            if (accIn) {
#pragma unroll
                for (int rg = 0; rg < 4; rg++)
                    acc[rg] = (float)accIn[(ri * 16 + lq * 4 + rg) * 40 + ci * 16 + lm];
            }
            bf16x8 af = *(const bf16x8*)(Ao + (ri * 16 + lm) * 40 + lq * 8);
            bf16x8 bf = *(const bf16x8*)(Bo + (ci * 16 + lm) * 40 + lq * 8);
            acc = MFMA16(af, bf, acc);
#pragma unroll
            for (int rg = 0; rg < 4; rg++) {
                int rr = ri * 16 + lq * 4 + rg, cc = ci * 16 + lm;
                __bf16 bv = (__bf16)acc[rg];
                if (oRm) oRm[rr * 40 + cc] = bv;
                if (oT)  oT[cc * 40 + rr] = bv;
            }
        }
        __syncthreads();
    };
    // T = (I+M)(I+M^2)(I+M^4)(I+M^8)(I+M^16)  (M nilpotent, order 32)
    mat32(Mrm, Mt, nullptr, M2rm, M2t);    // M^2
    mat32(Xa, M2t, Xa, Xb, nullptr);       // X2 = X(I+M^2)
    mat32(M2rm, M2t, nullptr, Mrm, Mt);    // M^4
    mat32(Xb, Mt, Xb, Xa, nullptr);        // X3
    mat32(Mrm, Mt, nullptr, M2rm, M2t);    // M^8
    mat32(Xa, M2t, Xa, Xb, nullptr);       // X4
    mat32(M2rm, M2t, nullptr, Mrm, Mt);    // M^16
    mat32(Xb, Mt, Xb, nullptr, Tt);        // T (stored [t'][s])
    mat32(Tt, Prm, nullptr, PTt, nullptr); // PTt[t'][s] = (P T)[s][t']

    // ATt[t'][n] = sum_{s<=t'} T[s][t'] * A~_s[n]  (scalar; Arm still live)
    for (int t2 = 0; t2 < 32; ++t2) {
        float a0 = 0.f, a1 = 0.f;
        for (int s = 0; s <= t2; ++s) {
            float tv = (float)Tt[t2 * 40 + s];
            a0 += tv * (float)Arm[s * 136 + n0];
            a1 += tv * (float)Arm[s * 136 + n1];
        }
        ATt_g[(size_t)u * 4096 + t2 * 128 + n0] = (__bf16)a0;
        ATt_g[(size_t)u * 4096 + t2 * 128 + n1] = (__bf16)a1;
    }
    // C_loc = V * (P T):  D[i][t'] = sum_s Vt[i][s] * PTt[t'][s]
#pragma unroll
    for (int ii = 0; ii < 8; ii++)
#pragma unroll
    for (int ti = 0; ti < 2; ti++) {
        f32x4 acc = {};
        bf16x8 af = *(const bf16x8*)(Vt + (ii * 16 + lm) * 40 + lq * 8);
        bf16x8 bf = *(const bf16x8*)(PTt + (ti * 16 + lm) * 40 + lq * 8);
        acc = MFMA16(af, bf, acc);
#pragma unroll
        for (int rg = 0; rg < 4; rg++)
            Cloc_g[(size_t)u * 4096 + (ii * 16 + lq * 4 + rg) * 32 + ti * 16 + lm] = acc[rg];
    }
}

// ---- phase B: per (head, 16-row block) = 128 blocks x 1 wave; 64 seq chunks ----
__global__ __launch_bounds__(64)
void scan_phaseB(const __bf16* __restrict__ ATt_g, const __bf16* __restrict__ Rr_g,
                 const __bf16* __restrict__ Bnt_g, const __bf16* __restrict__ Knt_g,
                 const __bf16* __restrict__ Vt_g, const __bf16* __restrict__ Gbt_g,
                 const __bf16* __restrict__ Gkt_g, const float* __restrict__ Cloc_g,
                 const float* __restrict__ cwL_g, float* __restrict__ yB) {
    __shared__ __align__(16) __bf16 Sbf[16 * 136];
    __shared__ __align__(16) __bf16 Cbf[16 * 40];
    __shared__ float Ybuf[32 * 18];
    const int h = blockIdx.y, i0 = blockIdx.x * 16;
    const int l = threadIdx.x, lm = l & 15, lq = l >> 4;
    f32x4 st[8];
#pragma unroll
    for (int cc = 0; cc < 8; cc++) st[cc] = (f32x4){0.f, 0.f, 0.f, 0.f};

    for (int c = 0; c < 64; ++c) {
        size_t u = (size_t)h * 64 + c;
        const __bf16* ATp = ATt_g + u * 4096;
        const __bf16* Rp  = Rr_g + u * 4096;
        const __bf16* Bp  = Bnt_g + u * 4096;
        const __bf16* Kp  = Knt_g + u * 4096;
        const __bf16* Vp  = Vt_g + u * 4096;
        const __bf16* Gbp = Gbt_g + u * 1024;
        const __bf16* Gkp = Gkt_g + u * 1024;
        const float*  Clp = Cloc_g + u * 4096;
        const float*  cwp = cwL_g + u * 128;
        // V A-frag [m=i][k=t]
        bf16x8 vf = *(const bf16x8*)(Vp + (i0 + lm) * 32 + lq * 8);
        // state -> bf16 LDS [i][n] (pad to 136)
#pragma unroll
        for (int cc = 0; cc < 8; cc++)
#pragma unroll
            for (int rg = 0; rg < 4; rg++)
                Sbf[(lq * 4 + rg) * 136 + cc * 16 + lm] = (__bf16)st[cc][rg];
        __syncthreads();
        bf16x8 saf[4];
#pragma unroll
        for (int s = 0; s < 4; s++)
            saf[s] = *(const bf16x8*)(Sbf + lm * 136 + s * 32 + lq * 8);
        // C = S0*AT + C_loc   (16 x 32)
        f32x4 cacc[2];
#pragma unroll
        for (int ti = 0; ti < 2; ti++) {
            f32x4 acc;
#pragma unroll
            for (int rg = 0; rg < 4; rg++)
                acc[rg] = Clp[(i0 + lq * 4 + rg) * 32 + ti * 16 + lm];
#pragma unroll
            for (int s = 0; s < 4; s++) {
                bf16x8 bf = *(const bf16x8*)(ATp + (ti * 16 + lm) * 128 + s * 32 + lq * 8);
                acc = MFMA16(saf[s], bf, acc);
            }
            cacc[ti] = acc;
        }
#pragma unroll
        for (int ti = 0; ti < 2; ti++)
#pragma unroll
            for (int rg = 0; rg < 4; rg++)
                Cbf[(lq * 4 + rg) * 40 + ti * 16 + lm] = (__bf16)cacc[ti][rg];
        __syncthreads();
        bf16x8 cf = *(const bf16x8*)(Cbf + lm * 40 + lq * 8);
        // Y = S0*R^ + C*Gb + V*Gk   (16 x 32)
#pragma unroll
        for (int ti = 0; ti < 2; ti++) {
            f32x4 acc = {};
#pragma unroll
            for (int s = 0; s < 4; s++) {
                bf16x8 bf = *(const bf16x8*)(Rp + (ti * 16 + lm) * 128 + s * 32 + lq * 8);
                acc = MFMA16(saf[s], bf, acc);
            }
            bf16x8 gb = *(const bf16x8*)(Gbp + (ti * 16 + lm) * 32 + lq * 8);
            acc = MFMA16(cf, gb, acc);
            bf16x8 gk = *(const bf16x8*)(Gkp + (ti * 16 + lm) * 32 + lq * 8);
            acc = MFMA16(vf, gk, acc);
#pragma unroll
            for (int rg = 0; rg < 4; rg++)
                Ybuf[(ti * 16 + lm) * 18 + lq * 4 + rg] = acc[rg];
        }
        __syncthreads();
#pragma unroll
        for (int pass = 0; pass < 8; pass++) {
            int t = pass * 4 + lq;
            yB[(size_t)(c * 32 + t) * 2048 + h * 128 + i0 + lm] = Ybuf[t * 18 + lm];
        }
        // S = (S0 + C*B^T + V*K^T) * cwL
#pragma unroll
        for (int cc = 0; cc < 8; cc++) {
            bf16x8 bb = *(const bf16x8*)(Bp + (cc * 16 + lm) * 32 + lq * 8);
            st[cc] = MFMA16(cf, bb, st[cc]);
            bf16x8 kb = *(const bf16x8*)(Kp + (cc * 16 + lm) * 32 + lq * 8);
            st[cc] = MFMA16(vf, kb, st[cc]);
            float cwv = cwp[cc * 16 + lm];
#pragma unroll
            for (int rg = 0; rg < 4; rg++) st[cc][rg] *= cwv;
        }
        __syncthreads();
    }
}

// ---------------- y -> bf16((y + c*v) * g) ----------------
__global__ void yg_kernel(const float* __restrict__ y, const float* __restrict__ cA,
                          const float* __restrict__ mega, const float* __restrict__ g,
                          __bf16* __restrict__ out) {
    int idx = blockIdx.x * 256 + threadIdx.x;
    int t = idx >> 11, col = idx & 2047;
    int h = col >> 7, n = col & 127, kv = h >> 2;
    float vf = mega[(size_t)t * 3072 + 2560 + kv * 128 + n];
    float val = (y[idx] + cA[t * 16 + h] * vf) * g[idx];
    out[idx] = (__bf16)val;
}

// ---------------- orchestration ----------------
extern "C" void kernel_launch(void* const* d_in, const int* in_sizes, int n_in,
                              void* d_out, int out_size, void* d_ws, size_t ws_size,
                              hipStream_t stream) {
    (void)in_sizes; (void)n_in; (void)out_size; (void)ws_size;
    const float* x      = (const float*)d_in[0];
    const float* vfirst = (const float*)d_in[1];
    const float* kfirst = (const float*)d_in[2];
    const float* amask  = (const float*)d_in[3];
    const float* cosT   = (const float*)d_in[4];
    const float* sinT   = (const float*)d_in[5];
    const float* w0     = (const float*)d_in[6];
    const float* w1     = (const float*)d_in[7];
    const float* w2     = (const float*)d_in[8];
    const float* a0     = (const float*)d_in[9];
    const float* a1     = (const float*)d_in[10];
    const float* a2     = (const float*)d_in[11];
    const float* v0     = (const float*)d_in[12];
    const float* v1     = (const float*)d_in[13];
    const float* v2     = (const float*)d_in[14];
    const float* k0     = (const float*)d_in[15];
    const float* k1     = (const float*)d_in[16];
    const float* k2     = (const float*)d_in[17];
    const float* g1     = (const float*)d_in[18];
    const float* g2     = (const float*)d_in[19];
    const float* rk     = (const float*)d_in[20];
    const float* rnw    = (const float*)d_in[21];
    const float* knw    = (const float*)d_in[22];
    const float* W_r    = (const float*)d_in[23];
    const float* W_k    = (const float*)d_in[24];
    const float* W_v    = (const float*)d_in[25];
    const float* W_o    = (const float*)d_in[26];

    char* p = (char*)d_ws;
    auto take = [&](size_t bytes) { char* r = p; p += (bytes + 255) & ~(size_t)255; return r; };
    __bf16* arena   = (__bf16*)take((size_t)3616 * 2048 * 2);
    __bf16* xmb     = (__bf16*)take((size_t)T_ * C_ * 2);
    float*  megaF   = (float*)take((size_t)T_ * 3072 * 4);
    __bf16* megaB   = (__bf16*)take((size_t)T_ * 544 * 2);
    __bf16* w2T     = (__bf16*)take((size_t)2048 * 160 * 2);
    __bf16* a2T     = (__bf16*)take((size_t)2048 * 96 * 2);
    __bf16* v2T     = (__bf16*)take((size_t)512 * 64 * 2);
    __bf16* k2T     = (__bf16*)take((size_t)512 * 64 * 2);
    __bf16* g2T     = (__bf16*)take((size_t)2048 * 160 * 2);
    float*  Wl      = (float*)take((size_t)T_ * 2048 * 4);
    float*  aS      = (float*)take((size_t)T_ * 2048 * 4);
    float*  gB      = (float*)take((size_t)T_ * 2048 * 4);
    float*  kkB     = (float*)take((size_t)T_ * 512 * 4);
    float*  vmx     = (float*)take((size_t)T_ * 512 * 4);
    float*  kmx     = (float*)take((size_t)T_ * 512 * 4);
    float*  yB      = (float*)take((size_t)T_ * 2048 * 4);
    float*  cB      = (float*)take((size_t)T_ * H_ * 4);
    // chunked-scan buffers (16 heads x 64 chunks = 1024 units)
    __bf16* ATt_g   = (__bf16*)take((size_t)1024 * 4096 * 2);
    __bf16* Rr_g    = (__bf16*)take((size_t)1024 * 4096 * 2);
    __bf16* Bnt_g   = (__bf16*)take((size_t)1024 * 4096 * 2);
    __bf16* Knt_g   = (__bf16*)take((size_t)1024 * 4096 * 2);
    __bf16* Vt_g    = (__bf16*)take((size_t)1024 * 4096 * 2);
    __bf16* Gbt_g   = (__bf16*)take((size_t)1024 * 1024 * 2);
    __bf16* Gkt_g   = (__bf16*)take((size_t)1024 * 1024 * 2);
    float*  Cloc_g  = (float*)take((size_t)1024 * 4096 * 4);
    float*  cwL_g   = (float*)take((size_t)1024 * 128 * 4);

    xm_to_bf16<<<(T_ * C_ / 4) / 256, 256, 0, stream>>>(x, amask, xmb);

    TrBatch tb;
    {
        const float* srcs[13] = {W_r, W_k, W_v, w1, a1, v1, k1, g1, w2, a2, v2, k2, g2};
        __bf16* dsts[13] = {arena, arena + (size_t)2048 * 2048, arena + (size_t)2560 * 2048,
                            arena + (size_t)3072 * 2048, arena + (size_t)3232 * 2048,
                            arena + (size_t)3328 * 2048, arena + (size_t)3392 * 2048,
                            arena + (size_t)3456 * 2048, w2T, a2T, v2T, k2T, g2T};
        int Rs[13] = {2048, 2048, 2048, 2048, 2048, 2048, 2048, 2048, 160, 96, 64, 64, 160};
        int Cs[13] = {2048, 512, 512, 160, 96, 64, 64, 160, 2048, 2048, 512, 512, 2048};
        int cum = 0;
        for (int e = 0; e < 13; e++) {
            tb.d[e].src = srcs[e]; tb.d[e].dst = dsts[e];
            tb.d[e].R = Rs[e]; tb.d[e].C = Cs[e]; tb.d[e].tileStart = cum;
            cum += ((Rs[e] + 31) / 32) * ((Cs[e] + 31) / 32);
        }
        tb.n = 13;
        transpose_batch<<<cum, 256, 0, stream>>>(tb);
    }

    gemm_bf16<2><<<dim3(29, 16), 256, 0, stream>>>(xmb, 2048, arena, nullptr, megaF, megaB, 3616, 2048, 0);

    gemm_bf16<0><<<dim3(16, 16), 256, 0, stream>>>(megaB + 0,   544, w2T, w0, Wl,  nullptr, 2048, 160, 0);
    gemm_bf16<0><<<dim3(16, 16), 256, 0, stream>>>(megaB + 160, 544, a2T, a0, aS,  nullptr, 2048, 96, 2);
    gemm_bf16<0><<<dim3(4, 16),  256, 0, stream>>>(megaB + 256, 544, v2T, v0, vmx, nullptr, 512, 64, 2);
    gemm_bf16<0><<<dim3(4, 16),  256, 0, stream>>>(megaB + 320, 544, k2T, k0, kmx, nullptr, 512, 64, 2);
    gemm_bf16<0><<<dim3(16, 16), 256, 0, stream>>>(megaB + 384, 544, g2T, nullptr, gB, nullptr, 2048, 160, 0);

    prep_kv<<<T_ * KVH_, 128, 0, stream>>>(megaF, kkB, kfirst, vfirst, kmx, vmx, cosT, sinT, knw);
    prep_r<<<T_ * H_, 128, 0, stream>>>(megaF, Wl, rk, cB, cosT, sinT, rnw);

    scan_phaseA<<<1024, 64, 0, stream>>>(Wl, megaF, aS, kkB, ATt_g, Rr_g, Bnt_g, Knt_g,
                                         Vt_g, Gbt_g, Gkt_g, Cloc_g, cwL_g);
    scan_phaseB<<<dim3(8, 16), 64, 0, stream>>>(ATt_g, Rr_g, Bnt_g, Knt_g, Vt_g,
                                                Gbt_g, Gkt_g, Cloc_g, cwL_g, yB);

    yg_kernel<<<(T_ * 2048) / 256, 256, 0, stream>>>(yB, cB, megaF, gB, xmb);

    transpose_f32_bf16<<<dim3(64, 64), 256, 0, stream>>>(W_o, arena, 2048, 2048);
    gemm_bf16<0><<<dim3(16, 16), 256, 0, stream>>>(xmb, 2048, arena, nullptr, (float*)d_out, nullptr, 2048, 2048, 0);
}

// Round 4
// 583.828 us; speedup vs baseline: 2.7286x; 1.6393x over previous
//
#include <hip/hip_runtime.h>
#include <hip/hip_bf16.h>
#include <math.h>

#define T_   2048
#define C_   2048
#define H_   16
#define N_   128
#define KVH_ 4

typedef __bf16 bf16x8 __attribute__((ext_vector_type(8)));
typedef __bf16 bf16x4 __attribute__((ext_vector_type(4)));
typedef float  f32x4  __attribute__((ext_vector_type(4)));

#define MFMA16(a, b, c) __builtin_amdgcn_mfma_f32_16x16x32_bf16(a, b, c, 0, 0, 0)

static __device__ __forceinline__ float wave_sum_shfl(float v) {
#pragma unroll
    for (int m = 32; m >= 1; m >>= 1) v += __shfl_xor(v, m, 64);
    return v;
}
static __device__ __forceinline__ float block_sum_128(float v, float* sh2) {
    v = wave_sum_shfl(v);
    if ((threadIdx.x & 63) == 0) sh2[threadIdx.x >> 6] = v;
    __syncthreads();
    float r = sh2[0] + sh2[1];
    __syncthreads();
    return r;
}

// ---------------- xm = bf16(x * mask) ----------------
__global__ void xm_to_bf16(const float* __restrict__ x, const float* __restrict__ mask,
                           __bf16* __restrict__ o) {
    int idx = blockIdx.x * 256 + threadIdx.x;
    int e = idx * 4;
    float4 v = *(const float4*)(x + e);
    float m = mask[e >> 11];
    bf16x4 r;
    r.x = (__bf16)(v.x * m); r.y = (__bf16)(v.y * m);
    r.z = (__bf16)(v.z * m); r.w = (__bf16)(v.w * m);
    *(bf16x4*)(o + e) = r;
}

// ---------------- batched tiled transpose f32 (R x C) -> bf16 (C x R) ----------------
struct TrDesc { const float* src; __bf16* dst; int R, C, tileStart; };
struct TrBatch { TrDesc d[13]; int n; };

__global__ void transpose_batch(TrBatch tb) {
    int bid = blockIdx.x;
    int e = 0;
    while (e + 1 < tb.n && tb.d[e + 1].tileStart <= bid) e++;
    const float* src = tb.d[e].src;
    __bf16* dst = tb.d[e].dst;
    int R = tb.d[e].R, C = tb.d[e].C;
    int tix = bid - tb.d[e].tileStart;
    int tilesC = (C + 31) >> 5;
    int trow = tix / tilesC, tcol = tix - trow * tilesC;
    int r0 = trow * 32, c0 = tcol * 32;
    __shared__ float tile[32][33];
    int tx = threadIdx.x & 31, ty = threadIdx.x >> 5;
#pragma unroll
    for (int i = 0; i < 4; i++) {
        int r = r0 + ty + i * 8, c = c0 + tx;
        if (r < R && c < C) tile[ty + i * 8][tx] = src[(size_t)r * C + c];
    }
    __syncthreads();
#pragma unroll
    for (int i = 0; i < 4; i++) {
        int c = c0 + ty + i * 8, r = r0 + tx;
        if (c < C && r < R) dst[(size_t)c * R + r] = (__bf16)tile[tx][ty + i * 8];
    }
}

__global__ void transpose_f32_bf16(const float* __restrict__ src, __bf16* __restrict__ dst,
                                   int R, int C) {
    __shared__ float tile[32][33];
    int tx = threadIdx.x & 31, ty = threadIdx.x >> 5;
    int c0 = blockIdx.x * 32, r0 = blockIdx.y * 32;
#pragma unroll
    for (int i = 0; i < 4; i++) {
        int r = r0 + ty + i * 8, c = c0 + tx;
        if (r < R && c < C) tile[ty + i * 8][tx] = src[(size_t)r * C + c];
    }
    __syncthreads();
#pragma unroll
    for (int i = 0; i < 4; i++) {
        int c = c0 + ty + i * 8, r = r0 + tx;
        if (c < C && r < R) dst[(size_t)c * R + r] = (__bf16)tile[tx][ty + i * 8];
    }
}

// ---------------- MFMA GEMM: C[M,N] = A[M,K] @ BT[N,K]^T ----------------
template <int MODE>
__global__ __launch_bounds__(256, 2)
void gemm_bf16(const __bf16* __restrict__ A, int lda, const __bf16* __restrict__ BT,
               const float* __restrict__ bias, float* __restrict__ Cf,
               __bf16* __restrict__ Cb, int N, int K, int act) {
    constexpr int LDK = 40;
    __shared__ __align__(16) __bf16 As[128 * LDK];
    __shared__ __align__(16) __bf16 Bs[128 * LDK];
    const int tid = threadIdx.x;
    const int lane = tid & 63, wave = tid >> 6;
    const int bm = blockIdx.y * 128, bn = blockIdx.x * 128;
    const int wm = (wave >> 1) * 64, wn = (wave & 1) * 64;
    const int srow = tid >> 1;
    const int skoff = (tid & 1) * 16;
    const __bf16* Ap = A + (size_t)(bm + srow) * lda + skoff;
    const __bf16* Bp = BT + (size_t)(bn + srow) * K + skoff;
    const bool bok = (bn + srow) < N;
    __bf16* AsW = As + srow * LDK + skoff;
    __bf16* BsW = Bs + srow * LDK + skoff;
    const int lm = lane & 15, lq = lane >> 4;
    f32x4 acc[4][4] = {};
    for (int k0 = 0; k0 < K; k0 += 32) {
        int4 a0 = *(const int4*)(Ap);
        int4 a1 = *(const int4*)(Ap + 8);
        int4 b0 = {0, 0, 0, 0}, b1 = {0, 0, 0, 0};
        if (bok) { b0 = *(const int4*)(Bp); b1 = *(const int4*)(Bp + 8); }
        __syncthreads();
        *(int4*)(AsW) = a0; *(int4*)(AsW + 8) = a1;
        *(int4*)(BsW) = b0; *(int4*)(BsW + 8) = b1;
        __syncthreads();
        bf16x8 af[4], bfr[4];
#pragma unroll
        for (int i = 0; i < 4; i++)
            af[i] = *(const bf16x8*)(As + (wm + i * 16 + lm) * LDK + lq * 8);
#pragma unroll
        for (int j = 0; j < 4; j++)
            bfr[j] = *(const bf16x8*)(Bs + (wn + j * 16 + lm) * LDK + lq * 8);
#pragma unroll
        for (int i = 0; i < 4; i++)
#pragma unroll
            for (int j = 0; j < 4; j++)
                acc[i][j] = MFMA16(af[i], bfr[j], acc[i][j]);
        Ap += 32; Bp += 32;
    }
#pragma unroll
    for (int j = 0; j < 4; j++) {
        int col = bn + wn + j * 16 + lm;
        if (col >= N) continue;
        float bv = (MODE == 0 && bias) ? bias[col] : 0.f;
#pragma unroll
        for (int i = 0; i < 4; i++) {
            int row0 = bm + wm + i * 16 + lq * 4;
#pragma unroll
            for (int rg = 0; rg < 4; rg++) {
                float v = acc[i][j][rg] + bv;
                int row = row0 + rg;
                if (MODE == 0) {
                    if (act == 1) v = tanhf(v);
                    else if (act == 2) v = 1.f / (1.f + __expf(-v));
                    Cf[(size_t)row * N + col] = v;
                } else {
                    if (col < 3072) {
                        Cf[(size_t)row * 3072 + col] = v;
                    } else {
                        float vv = v;
                        if (col < 3232) vv = tanhf(v);
                        else if (col >= 3456) vv = 1.f / (1.f + __expf(-v));
                        Cb[(size_t)row * 544 + (col - 3072)] = (__bf16)vv;
                    }
                }
            }
        }
    }
}

// ---------------- prep for k/v (per (t,kvh)); mega row stride 3072 ----------------
__global__ __launch_bounds__(128)
void prep_kv(float* __restrict__ mega, float* __restrict__ kkO,
             const float* __restrict__ kfirst, const float* __restrict__ vfirst,
             const float* __restrict__ kmix, const float* __restrict__ vmix,
             const float* __restrict__ cosT, const float* __restrict__ sinT,
             const float* __restrict__ knw) {
    __shared__ float sh[128];
    __shared__ float sh2[2];
    int b = blockIdx.x;
    int t = b >> 2, kvh = b & 3;
    int n = threadIdx.x;
    size_t kbase = (size_t)t * 3072 + 2048 + kvh * 128;
    size_t vbase = (size_t)t * 3072 + 2560 + kvh * 128;
    size_t fbase = (size_t)t * 512 + kvh * 128;
    float x = mega[kbase + n];
    float ssq = block_sum_128(x * x, sh2);
    float kn = knw[n] * (x * rsqrtf(ssq * (1.f / 128.f) + 1e-6f));
    sh[n] = kn;
    __syncthreads();
    float rot = (n < 64) ? -sh[n + 64] : sh[n - 64];
    float c = cosT[(size_t)t * 128 + n], s = sinT[(size_t)t * 128 + n];
    float kr = kn * c + rot * s;
    float kf = kr + (kfirst[fbase + n] - kr) * kmix[fbase + n];
    float s2 = block_sum_128(kf * kf, sh2);
    float kkv = kf / fmaxf(sqrtf(s2), 1e-12f);
    float vv = mega[vbase + n];
    float vf = vv + (vfirst[fbase + n] - vv) * vmix[fbase + n];
    mega[kbase + n] = kf;
    kkO[fbase + n] = kkv;
    mega[vbase + n] = vf;
}

// ---------------- prep for r / wdec / c (per (t,h)) ----------------
__global__ __launch_bounds__(128)
void prep_r(float* __restrict__ mega, float* __restrict__ Wl,
            const float* __restrict__ rk, float* __restrict__ cOut,
            const float* __restrict__ cosT, const float* __restrict__ sinT,
            const float* __restrict__ rnw) {
    __shared__ float sh[128];
    __shared__ float sh2[2];
    int b = blockIdx.x;
    int t = b >> 4, h = b & 15;
    int kv = h >> 2;
    int n = threadIdx.x;
    size_t rbase = (size_t)t * 3072 + h * 128;
    float x = mega[rbase + n];
    float ssq = block_sum_128(x * x, sh2);
    float rn = rnw[n] * (x * rsqrtf(ssq * (1.f / 128.f) + 1e-6f));
    sh[n] = rn;
    __syncthreads();
    float rot = (n < 64) ? -sh[n + 64] : sh[n - 64];
    float c = cosT[(size_t)t * 128 + n], s = sinT[(size_t)t * 128 + n];
    float rr = rn * c + rot * s;
    mega[rbase + n] = rr;
    size_t wb_ = (size_t)t * 2048 + h * 128 + n;
    float z = Wl[wb_];
    float nz = -z;
    float sp = fmaxf(nz, 0.f) + log1pf(expf(-fabsf(nz)));
    float w = -sp - 0.5f;
    Wl[wb_] = expf(-expf(w));
    float pc = rr * mega[(size_t)t * 3072 + 2048 + kv * 128 + n] * rk[h * 128 + n];
    float cs = block_sum_128(pc, sh2);
    if (n == 0) cOut[b] = cs;
}

// =====================================================================
// Chunked scan, L=32, 64 chunks (WY/UT transform). PhaseA builds per-chunk
// operands; phaseB (sequential, state only) propagates S and dumps S0/C;
// phaseC (parallel) computes Y and fuses the output gating.
// =====================================================================

// ---- phase A: per (head, chunk) = 1024 blocks x 1 wave -------------
__global__ __launch_bounds__(64)
void scan_phaseA(const float* __restrict__ Wl, const float* __restrict__ megaF,
                 const float* __restrict__ aS, const float* __restrict__ kkB,
                 __bf16* __restrict__ ATt_g, __bf16* __restrict__ Rr_g,
                 __bf16* __restrict__ Bnt_g, __bf16* __restrict__ Knt_g,
                 __bf16* __restrict__ Vt_g, __bf16* __restrict__ Gbt_g,
                 __bf16* __restrict__ Gkt_g, float* __restrict__ Cloc_g,
                 float* __restrict__ cwL_g) {
    __shared__ __align__(16) __bf16 pool[27648];
    __bf16* Arm = pool;            // [32][136]
    __bf16* Brm = pool + 4352;     // [32][136]
    __bf16* Krm = pool + 8704;     // [32][136]
    __bf16* Rrm = pool + 13056;    // [32][136]
    __bf16* Vt  = pool + 17408;    // [128][40]
    __bf16* Mrm = pool + 22528;    // [32][40]
    __bf16* Mt  = pool + 23808;    // [32][40]
    __bf16* Prm = pool + 25088;    // [32][40]
    __bf16* Gtmp= pool + 26368;    // [32][40]
    __bf16* M2rm = pool + 4352;
    __bf16* M2t  = pool + 5632;
    __bf16* Xa   = pool + 6912;
    __bf16* Xb   = pool + 8192;
    __bf16* Tt   = pool + 9472;    // [t'][s] = T[s][t']
    __bf16* PTt  = pool + 10752;   // [t'][s] = (P*T)[s][t']

    const int l = threadIdx.x, lm = l & 15, lq = l >> 4;
    const int u = blockIdx.x, h = u >> 6, c = u & 63, kv = h >> 2;
    const int n0 = l, n1 = l + 64;

    float cw0 = 1.f, cw1 = 1.f;
    for (int t = 0; t < 32; ++t) {
        int tg = c * 32 + t;
        size_t hb = (size_t)tg * 2048 + h * 128;
        size_t mb = (size_t)tg * 3072;
        size_t kb = (size_t)tg * 512 + kv * 128;
        float wv0 = Wl[hb + n0], wv1 = Wl[hb + n1];
        float r0 = megaF[mb + h * 128 + n0], r1 = megaF[mb + h * 128 + n1];
        float q0 = kkB[kb + n0], q1 = kkB[kb + n1];
        float s0 = aS[hb + n0], s1 = aS[hb + n1];
        float k0 = megaF[mb + 2048 + kv * 128 + n0], k1 = megaF[mb + 2048 + kv * 128 + n1];
        float v0 = megaF[mb + 2560 + kv * 128 + n0], v1 = megaF[mb + 2560 + kv * 128 + n1];
        float cp0 = cw0, cp1 = cw1;
        cw0 *= wv0; cw1 *= wv1;
        float ic0 = 1.f / cw0, ic1 = 1.f / cw1;
        Arm[t * 136 + n0] = (__bf16)(-cp0 * q0);
        Arm[t * 136 + n1] = (__bf16)(-cp1 * q1);
        Brm[t * 136 + n0] = (__bf16)(q0 * s0 * ic0);
        Brm[t * 136 + n1] = (__bf16)(q1 * s1 * ic1);
        Krm[t * 136 + n0] = (__bf16)(k0 * ic0);
        Krm[t * 136 + n1] = (__bf16)(k1 * ic1);
        Rrm[t * 136 + n0] = (__bf16)(cw0 * r0);
        Rrm[t * 136 + n1] = (__bf16)(cw1 * r1);
        Vt[n0 * 40 + t] = (__bf16)v0;
        Vt[n1 * 40 + t] = (__bf16)v1;
    }
    cwL_g[(size_t)u * 128 + n0] = cw0;
    cwL_g[(size_t)u * 128 + n1] = cw1;
    __syncthreads();

    auto mmLL = [&](const __bf16* Ao, const __bf16* Bo, bool incl, __bf16* dTr, __bf16* dDir) {
#pragma unroll
        for (int ri = 0; ri < 2; ri++)
#pragma unroll
        for (int ci = 0; ci < 2; ci++) {
            f32x4 acc = {};
#pragma unroll
            for (int s = 0; s < 4; s++) {
                bf16x8 af = *(const bf16x8*)(Ao + (ri * 16 + lm) * 136 + s * 32 + lq * 8);
                bf16x8 bf = *(const bf16x8*)(Bo + (ci * 16 + lm) * 136 + s * 32 + lq * 8);
                acc = MFMA16(af, bf, acc);
            }
#pragma unroll
            for (int rg = 0; rg < 4; rg++) {
                int rr = ri * 16 + lq * 4 + rg, cc = ci * 16 + lm;
                bool keep = incl ? (cc <= rr) : (cc < rr);
                __bf16 bv = (__bf16)(keep ? acc[rg] : 0.f);
                if (dTr)  dTr[cc * 40 + rr] = bv;
                if (dDir) dDir[rr * 40 + cc] = bv;
            }
        }
    };
    mmLL(Arm, Brm, false, Mrm, Mt);
    mmLL(Arm, Krm, false, Prm, nullptr);
    mmLL(Rrm, Brm, true, nullptr, Gtmp);
    __syncthreads();
    for (int i = l; i < 512; i += 64) {
        int r = i >> 4, cp = i & 15;
        ((int*)(Gbt_g + (size_t)u * 1024))[i] = *(const int*)(Gtmp + r * 40 + cp * 2);
    }
    __syncthreads();
    mmLL(Rrm, Krm, true, nullptr, Gtmp);
    __syncthreads();
    for (int i = l; i < 512; i += 64) {
        int r = i >> 4, cp = i & 15;
        ((int*)(Gkt_g + (size_t)u * 1024))[i] = *(const int*)(Gtmp + r * 40 + cp * 2);
    }
    for (int i = l; i < 2048; i += 64) {
        int t = i >> 6, cp = i & 63;
        ((int*)(Rr_g + (size_t)u * 4096))[i] = *(const int*)(Rrm + t * 136 + cp * 2);
    }
    for (int i = l; i < 2048; i += 64) {
        int n = i >> 4, tp = i & 15;
        unsigned int lo = ((const unsigned short*)Brm)[(2 * tp) * 136 + n];
        unsigned int hi = ((const unsigned short*)Brm)[(2 * tp + 1) * 136 + n];
        ((unsigned int*)(Bnt_g + (size_t)u * 4096))[i] = lo | (hi << 16);
        unsigned int lo2 = ((const unsigned short*)Krm)[(2 * tp) * 136 + n];
        unsigned int hi2 = ((const unsigned short*)Krm)[(2 * tp + 1) * 136 + n];
        ((unsigned int*)(Knt_g + (size_t)u * 4096))[i] = lo2 | (hi2 << 16);
    }
    for (int i = l; i < 2048; i += 64) {
        int n = i >> 4, tp = i & 15;
        ((int*)(Vt_g + (size_t)u * 4096))[i] = *(const int*)(Vt + n * 40 + tp * 2);
    }
    __syncthreads();

    for (int i = l; i < 1024; i += 64) {
        int s = i >> 5, t = i & 31;
        Xa[s * 40 + t] = (s == t) ? (__bf16)1.f : Mrm[s * 40 + t];
    }
    __syncthreads();

    auto mat32 = [&](const __bf16* Ao, const __bf16* Bo, const __bf16* accIn,
                     __bf16* oRm, __bf16* oT) {
#pragma unroll
        for (int ri = 0; ri < 2; ri++)
#pragma unroll
        for (int ci = 0; ci < 2; ci++) {
            f32x4 acc = {};
            if (accIn) {
#pragma unroll
                for (int rg = 0; rg < 4; rg++)
                    acc[rg] = (float)accIn[(ri * 16 + lq * 4 + rg) * 40 + ci * 16 + lm];
            }
            bf16x8 af = *(const bf16x8*)(Ao + (ri * 16 + lm) * 40 + lq * 8);
            bf16x8 bf = *(const bf16x8*)(Bo + (ci * 16 + lm) * 40 + lq * 8);
            acc = MFMA16(af, bf, acc);
#pragma unroll
            for (int rg = 0; rg < 4; rg++) {
                int rr = ri * 16 + lq * 4 + rg, cc = ci * 16 + lm;
                __bf16 bv = (__bf16)acc[rg];
                if (oRm) oRm[rr * 40 + cc] = bv;
                if (oT)  oT[cc * 40 + rr] = bv;
            }
        }
        __syncthreads();
    };
    mat32(Mrm, Mt, nullptr, M2rm, M2t);
    mat32(Xa, M2t, Xa, Xb, nullptr);
    mat32(M2rm, M2t, nullptr, Mrm, Mt);
    mat32(Xb, Mt, Xb, Xa, nullptr);
    mat32(Mrm, Mt, nullptr, M2rm, M2t);
    mat32(Xa, M2t, Xa, Xb, nullptr);
    mat32(M2rm, M2t, nullptr, Mrm, Mt);
    mat32(Xb, Mt, Xb, nullptr, Tt);
    mat32(Tt, Prm, nullptr, PTt, nullptr);

    for (int t2 = 0; t2 < 32; ++t2) {
        float a0 = 0.f, a1 = 0.f;
        for (int s = 0; s <= t2; ++s) {
            float tv = (float)Tt[t2 * 40 + s];
            a0 += tv * (float)Arm[s * 136 + n0];
            a1 += tv * (float)Arm[s * 136 + n1];
        }
        ATt_g[(size_t)u * 4096 + t2 * 128 + n0] = (__bf16)a0;
        ATt_g[(size_t)u * 4096 + t2 * 128 + n1] = (__bf16)a1;
    }
#pragma unroll
    for (int ii = 0; ii < 8; ii++)
#pragma unroll
    for (int ti = 0; ti < 2; ti++) {
        f32x4 acc = {};
        bf16x8 af = *(const bf16x8*)(Vt + (ii * 16 + lm) * 40 + lq * 8);
        bf16x8 bf = *(const bf16x8*)(PTt + (ti * 16 + lm) * 40 + lq * 8);
        acc = MFMA16(af, bf, acc);
#pragma unroll
        for (int rg = 0; rg < 4; rg++)
            Cloc_g[(size_t)u * 4096 + (ii * 16 + lq * 4 + rg) * 32 + ti * 16 + lm] = acc[rg];
    }
}

// ---- phase B: state propagation only. 128 blocks x 1 wave, 64 seq chunks ----
// Stores S0 (A-frag layout) and C per chunk for the parallel Y phase.
struct Ops {
    bf16x8 at[8], bn[8], kn[8], vf;
    f32x4 cl[2];
    float cw[8];
};

__global__ __launch_bounds__(64, 1)
void scan_phaseB(const __bf16* __restrict__ ATt_g, const __bf16* __restrict__ Bnt_g,
                 const __bf16* __restrict__ Knt_g, const __bf16* __restrict__ Vt_g,
                 const float* __restrict__ Cloc_g, const float* __restrict__ cwL_g,
                 __bf16* __restrict__ Sg, __bf16* __restrict__ Cg) {
    __shared__ __align__(16) __bf16 Sbf[16 * 136];
    __shared__ __align__(16) __bf16 Cbf[16 * 40];
    const int h = blockIdx.y, i0 = blockIdx.x * 16;
    const int l = threadIdx.x, lm = l & 15, lq = l >> 4;
    f32x4 st[8];
#pragma unroll
    for (int cc = 0; cc < 8; cc++) st[cc] = (f32x4){0.f, 0.f, 0.f, 0.f};

    auto loadOps = [&](int c, Ops& o) {
        size_t u = (size_t)h * 64 + c;
        const __bf16* ATp = ATt_g + u * 4096;
        const __bf16* Bp  = Bnt_g + u * 4096;
        const __bf16* Kp  = Knt_g + u * 4096;
#pragma unroll
        for (int ti = 0; ti < 2; ti++)
#pragma unroll
            for (int s = 0; s < 4; s++)
                o.at[ti * 4 + s] = *(const bf16x8*)(ATp + (ti * 16 + lm) * 128 + s * 32 + lq * 8);
#pragma unroll
        for (int cc = 0; cc < 8; cc++) {
            o.bn[cc] = *(const bf16x8*)(Bp + (cc * 16 + lm) * 32 + lq * 8);
            o.kn[cc] = *(const bf16x8*)(Kp + (cc * 16 + lm) * 32 + lq * 8);
        }
        o.vf = *(const bf16x8*)(Vt_g + u * 4096 + (i0 + lm) * 32 + lq * 8);
#pragma unroll
        for (int ti = 0; ti < 2; ti++)
#pragma unroll
            for (int rg = 0; rg < 4; rg++)
                o.cl[ti][rg] = Cloc_g[u * 4096 + (i0 + lq * 4 + rg) * 32 + ti * 16 + lm];
#pragma unroll
        for (int cc = 0; cc < 8; cc++) o.cw[cc] = cwL_g[u * 128 + cc * 16 + lm];
    };

    auto computeChunk = [&](int c, const Ops& o) {
        size_t u = (size_t)h * 64 + c;
#pragma unroll
        for (int cc = 0; cc < 8; cc++)
#pragma unroll
            for (int rg = 0; rg < 4; rg++)
                Sbf[(lq * 4 + rg) * 136 + cc * 16 + lm] = (__bf16)st[cc][rg];
        __syncthreads();
        bf16x8 saf[4];
#pragma unroll
        for (int s = 0; s < 4; s++)
            saf[s] = *(const bf16x8*)(Sbf + lm * 136 + s * 32 + lq * 8);
        f32x4 cacc[2];
#pragma unroll
        for (int ti = 0; ti < 2; ti++) {
            f32x4 acc = o.cl[ti];
#pragma unroll
            for (int s = 0; s < 4; s++) acc = MFMA16(saf[s], o.at[ti * 4 + s], acc);
            cacc[ti] = acc;
        }
#pragma unroll
        for (int ti = 0; ti < 2; ti++)
#pragma unroll
            for (int rg = 0; rg < 4; rg++)
                Cbf[(lq * 4 + rg) * 40 + ti * 16 + lm] = (__bf16)cacc[ti][rg];
        __syncthreads();
        bf16x8 cf = *(const bf16x8*)(Cbf + lm * 40 + lq * 8);
        // dump S0 (A-frag layout) and C for phaseC — off the dependency chain
#pragma unroll
        for (int s = 0; s < 4; s++)
            *(bf16x8*)(Sg + u * 16384 + (size_t)(i0 + lm) * 128 + s * 32 + lq * 8) = saf[s];
        *(bf16x8*)(Cg + u * 4096 + (size_t)(i0 + lm) * 32 + lq * 8) = cf;
        // S = (S0 + C*B^T + V*K^T) * cwL
#pragma unroll
        for (int cc = 0; cc < 8; cc++) {
            st[cc] = MFMA16(cf, o.bn[cc], st[cc]);
            st[cc] = MFMA16(o.vf, o.kn[cc], st[cc]);
#pragma unroll
            for (int rg = 0; rg < 4; rg++) st[cc][rg] *= o.cw[cc];
        }
        __syncthreads();
    };

    Ops A, B;
    loadOps(0, A);
    loadOps(1, B);
    for (int c = 0; c < 64; c += 2) {
        computeChunk(c, A);
        if (c + 2 < 64) loadOps(c + 2, A);
        computeChunk(c + 1, B);
        if (c + 3 < 64) loadOps(c + 3, B);
    }
}

// ---- phase C: Y = S0*R^ + C*Gb + V*Gk, fused output gating ----
// grid (64 chunks * 8 iblocks, 16 heads) x 64 threads
__global__ __launch_bounds__(64)
void scan_phaseC(const __bf16* __restrict__ Sg, const __bf16* __restrict__ Cg,
                 const __bf16* __restrict__ Rr_g, const __bf16* __restrict__ Vt_g,
                 const __bf16* __restrict__ Gbt_g, const __bf16* __restrict__ Gkt_g,
                 const float* __restrict__ cB, const float* __restrict__ megaF,
                 const float* __restrict__ gB, __bf16* __restrict__ out) {
    __shared__ float Ybuf[32 * 18];
    const int bx = blockIdx.x, h = blockIdx.y;
    const int c = bx >> 3, i0 = (bx & 7) * 16;
    const int l = threadIdx.x, lm = l & 15, lq = l >> 4;
    const size_t u = (size_t)h * 64 + c;
    bf16x8 saf[4];
#pragma unroll
    for (int s = 0; s < 4; s++)
        saf[s] = *(const bf16x8*)(Sg + u * 16384 + (size_t)(i0 + lm) * 128 + s * 32 + lq * 8);
    bf16x8 cf = *(const bf16x8*)(Cg + u * 4096 + (size_t)(i0 + lm) * 32 + lq * 8);
    bf16x8 vf = *(const bf16x8*)(Vt_g + u * 4096 + (size_t)(i0 + lm) * 32 + lq * 8);
#pragma unroll
    for (int ti = 0; ti < 2; ti++) {
        f32x4 acc = {};
#pragma unroll
        for (int s = 0; s < 4; s++) {
            bf16x8 rp = *(const bf16x8*)(Rr_g + u * 4096 + (ti * 16 + lm) * 128 + s * 32 + lq * 8);
            acc = MFMA16(saf[s], rp, acc);
        }
        bf16x8 gb = *(const bf16x8*)(Gbt_g + u * 1024 + (ti * 16 + lm) * 32 + lq * 8);
        acc = MFMA16(cf, gb, acc);
        bf16x8 gk = *(const bf16x8*)(Gkt_g + u * 1024 + (ti * 16 + lm) * 32 + lq * 8);
        acc = MFMA16(vf, gk, acc);
#pragma unroll
        for (int rg = 0; rg < 4; rg++)
            Ybuf[(ti * 16 + lm) * 18 + lq * 4 + rg] = acc[rg];
    }
    __syncthreads();
    const int kv = h >> 2;
#pragma unroll
    for (int pass = 0; pass < 8; pass++) {
        int t = pass * 4 + lq;
        int tg = c * 32 + t;
        int col = h * 128 + i0 + lm;
        float yv = Ybuf[t * 18 + lm];
        float cv = cB[tg * 16 + h];
        float vv = megaF[(size_t)tg * 3072 + 2560 + kv * 128 + i0 + lm];
        float gg = gB[(size_t)tg * 2048 + col];
        out[(size_t)tg * 2048 + col] = (__bf16)((yv + cv * vv) * gg);
    }
}

// ---------------- orchestration ----------------
extern "C" void kernel_launch(void* const* d_in, const int* in_sizes, int n_in,
                              void* d_out, int out_size, void* d_ws, size_t ws_size,
                              hipStream_t stream) {
    (void)in_sizes; (void)n_in; (void)out_size; (void)ws_size;
    const float* x      = (const float*)d_in[0];
    const float* vfirst = (const float*)d_in[1];
    const float* kfirst = (const float*)d_in[2];
    const float* amask  = (const float*)d_in[3];
    const float* cosT   = (const float*)d_in[4];
    const float* sinT   = (const float*)d_in[5];
    const float* w0     = (const float*)d_in[6];
    const float* w1     = (const float*)d_in[7];
    const float* w2     = (const float*)d_in[8];
    const float* a0     = (const float*)d_in[9];
    const float* a1     = (const float*)d_in[10];
    const float* a2     = (const float*)d_in[11];
    const float* v0     = (const float*)d_in[12];
    const float* v1     = (const float*)d_in[13];
    const float* v2     = (const float*)d_in[14];
    const float* k0     = (const float*)d_in[15];
    const float* k1     = (const float*)d_in[16];
    const float* k2     = (const float*)d_in[17];
    const float* g1     = (const float*)d_in[18];
    const float* g2     = (const float*)d_in[19];
    const float* rk     = (const float*)d_in[20];
    const float* rnw    = (const float*)d_in[21];
    const float* knw    = (const float*)d_in[22];
    const float* W_r    = (const float*)d_in[23];
    const float* W_k    = (const float*)d_in[24];
    const float* W_v    = (const float*)d_in[25];
    const float* W_o    = (const float*)d_in[26];

    char* p = (char*)d_ws;
    auto take = [&](size_t bytes) { char* r = p; p += (bytes + 255) & ~(size_t)255; return r; };
    __bf16* arena   = (__bf16*)take((size_t)3616 * 2048 * 2);
    __bf16* xmb     = (__bf16*)take((size_t)T_ * C_ * 2);
    float*  megaF   = (float*)take((size_t)T_ * 3072 * 4);
    __bf16* megaB   = (__bf16*)take((size_t)T_ * 544 * 2);
    __bf16* w2T     = (__bf16*)take((size_t)2048 * 160 * 2);
    __bf16* a2T     = (__bf16*)take((size_t)2048 * 96 * 2);
    __bf16* v2T     = (__bf16*)take((size_t)512 * 64 * 2);
    __bf16* k2T     = (__bf16*)take((size_t)512 * 64 * 2);
    __bf16* g2T     = (__bf16*)take((size_t)2048 * 160 * 2);
    float*  Wl      = (float*)take((size_t)T_ * 2048 * 4);   // w_lin -> wdec; reused as Sg
    float*  aS      = (float*)take((size_t)T_ * 2048 * 4);   // a; tail of Sg
    float*  gB      = (float*)take((size_t)T_ * 2048 * 4);
    float*  kkB     = (float*)take((size_t)T_ * 512 * 4);    // kk; reused as Cg
    float*  vmx     = (float*)take((size_t)T_ * 512 * 4);    // tail of Cg
    float*  kmx     = (float*)take((size_t)T_ * 512 * 4);
    float*  cB      = (float*)take((size_t)T_ * H_ * 4);
    __bf16* ATt_g   = (__bf16*)take((size_t)1024 * 4096 * 2);
    __bf16* Rr_g    = (__bf16*)take((size_t)1024 * 4096 * 2);
    __bf16* Bnt_g   = (__bf16*)take((size_t)1024 * 4096 * 2);
    __bf16* Knt_g   = (__bf16*)take((size_t)1024 * 4096 * 2);
    __bf16* Vt_g    = (__bf16*)take((size_t)1024 * 4096 * 2);
    __bf16* Gbt_g   = (__bf16*)take((size_t)1024 * 1024 * 2);
    __bf16* Gkt_g   = (__bf16*)take((size_t)1024 * 1024 * 2);
    float*  Cloc_g  = (float*)take((size_t)1024 * 4096 * 4);
    float*  cwL_g   = (float*)take((size_t)1024 * 128 * 4);
    // aliases (dead after phaseA): S0 dump (32MB over Wl+aS), C dump (8MB over kkB+vmx)
    __bf16* Sg = (__bf16*)Wl;
    __bf16* Cg = (__bf16*)kkB;

    xm_to_bf16<<<(T_ * C_ / 4) / 256, 256, 0, stream>>>(x, amask, xmb);

    TrBatch tb;
    {
        const float* srcs[13] = {W_r, W_k, W_v, w1, a1, v1, k1, g1, w2, a2, v2, k2, g2};
        __bf16* dsts[13] = {arena, arena + (size_t)2048 * 2048, arena + (size_t)2560 * 2048,
                            arena + (size_t)3072 * 2048, arena + (size_t)3232 * 2048,
                            arena + (size_t)3328 * 2048, arena + (size_t)3392 * 2048,
                            arena + (size_t)3456 * 2048, w2T, a2T, v2T, k2T, g2T};
        int Rs[13] = {2048, 2048, 2048, 2048, 2048, 2048, 2048, 2048, 160, 96, 64, 64, 160};
        int Cs[13] = {2048, 512, 512, 160, 96, 64, 64, 160, 2048, 2048, 512, 512, 2048};
        int cum = 0;
        for (int e = 0; e < 13; e++) {
            tb.d[e].src = srcs[e]; tb.d[e].dst = dsts[e];
            tb.d[e].R = Rs[e]; tb.d[e].C = Cs[e]; tb.d[e].tileStart = cum;
            cum += ((Rs[e] + 31) / 32) * ((Cs[e] + 31) / 32);
        }
        tb.n = 13;
        transpose_batch<<<cum, 256, 0, stream>>>(tb);
    }

    gemm_bf16<2><<<dim3(29, 16), 256, 0, stream>>>(xmb, 2048, arena, nullptr, megaF, megaB, 3616, 2048, 0);

    gemm_bf16<0><<<dim3(16, 16), 256, 0, stream>>>(megaB + 0,   544, w2T, w0, Wl,  nullptr, 2048, 160, 0);
    gemm_bf16<0><<<dim3(16, 16), 256, 0, stream>>>(megaB + 160, 544, a2T, a0, aS,  nullptr, 2048, 96, 2);
    gemm_bf16<0><<<dim3(4, 16),  256, 0, stream>>>(megaB + 256, 544, v2T, v0, vmx, nullptr, 512, 64, 2);
    gemm_bf16<0><<<dim3(4, 16),  256, 0, stream>>>(megaB + 320, 544, k2T, k0, kmx, nullptr, 512, 64, 2);
    gemm_bf16<0><<<dim3(16, 16), 256, 0, stream>>>(megaB + 384, 544, g2T, nullptr, gB, nullptr, 2048, 160, 0);

    prep_kv<<<T_ * KVH_, 128, 0, stream>>>(megaF, kkB, kfirst, vfirst, kmx, vmx, cosT, sinT, knw);
    prep_r<<<T_ * H_, 128, 0, stream>>>(megaF, Wl, rk, cB, cosT, sinT, rnw);

    scan_phaseA<<<1024, 64, 0, stream>>>(Wl, megaF, aS, kkB, ATt_g, Rr_g, Bnt_g, Knt_g,
                                         Vt_g, Gbt_g, Gkt_g, Cloc_g, cwL_g);
    scan_phaseB<<<dim3(8, 16), 64, 0, stream>>>(ATt_g, Bnt_g, Knt_g, Vt_g, Cloc_g, cwL_g, Sg, Cg);
    scan_phaseC<<<dim3(512, 16), 64, 0, stream>>>(Sg, Cg, Rr_g, Vt_g, Gbt_g, Gkt_g,
                                                  cB, megaF, gB, xmb);

    transpose_f32_bf16<<<dim3(64, 64), 256, 0, stream>>>(W_o, arena, 2048, 2048);
    gemm_bf16<0><<<dim3(16, 16), 256, 0, stream>>>(xmb, 2048, arena, nullptr, (float*)d_out, nullptr, 2048, 2048, 0);
}

// Round 5
// 503.496 us; speedup vs baseline: 3.1639x; 1.1595x over previous
//
#include <hip/hip_runtime.h>
#include <hip/hip_bf16.h>
#include <math.h>

#define T_   2048
#define C_   2048
#define H_   16
#define N_   128
#define KVH_ 4

typedef __bf16 bf16x8 __attribute__((ext_vector_type(8)));
typedef __bf16 bf16x4 __attribute__((ext_vector_type(4)));
typedef float  f32x4  __attribute__((ext_vector_type(4)));

#define MFMA16(a, b, c) __builtin_amdgcn_mfma_f32_16x16x32_bf16(a, b, c, 0, 0, 0)

// async global->LDS, 16B per lane; LDS dest = wave-uniform base + lane*16
static __device__ __forceinline__ void gll16(const __bf16* g, __bf16* l) {
    __builtin_amdgcn_global_load_lds((const __attribute__((address_space(1))) void*)g,
                                     (__attribute__((address_space(3))) void*)l, 16, 0, 0);
}

static __device__ __forceinline__ float wave_sum_shfl(float v) {
#pragma unroll
    for (int m = 32; m >= 1; m >>= 1) v += __shfl_xor(v, m, 64);
    return v;
}
static __device__ __forceinline__ float block_sum_128(float v, float* sh2) {
    v = wave_sum_shfl(v);
    if ((threadIdx.x & 63) == 0) sh2[threadIdx.x >> 6] = v;
    __syncthreads();
    float r = sh2[0] + sh2[1];
    __syncthreads();
    return r;
}

// ---------------- xm = bf16(x * mask) ----------------
__global__ void xm_to_bf16(const float* __restrict__ x, const float* __restrict__ mask,
                           __bf16* __restrict__ o) {
    int idx = blockIdx.x * 256 + threadIdx.x;
    int e = idx * 4;
    float4 v = *(const float4*)(x + e);
    float m = mask[e >> 11];
    bf16x4 r;
    r.x = (__bf16)(v.x * m); r.y = (__bf16)(v.y * m);
    r.z = (__bf16)(v.z * m); r.w = (__bf16)(v.w * m);
    *(bf16x4*)(o + e) = r;
}

// ---------------- batched tiled transpose f32 (R x C) -> bf16 (C x R) ----------------
struct TrDesc { const float* src; __bf16* dst; int R, C, tileStart; };
struct TrBatch { TrDesc d[13]; int n; };

__global__ void transpose_batch(TrBatch tb) {
    int bid = blockIdx.x;
    int e = 0;
    while (e + 1 < tb.n && tb.d[e + 1].tileStart <= bid) e++;
    const float* src = tb.d[e].src;
    __bf16* dst = tb.d[e].dst;
    int R = tb.d[e].R, C = tb.d[e].C;
    int tix = bid - tb.d[e].tileStart;
    int tilesC = (C + 31) >> 5;
    int trow = tix / tilesC, tcol = tix - trow * tilesC;
    int r0 = trow * 32, c0 = tcol * 32;
    __shared__ float tile[32][33];
    int tx = threadIdx.x & 31, ty = threadIdx.x >> 5;
#pragma unroll
    for (int i = 0; i < 4; i++) {
        int r = r0 + ty + i * 8, c = c0 + tx;
        if (r < R && c < C) tile[ty + i * 8][tx] = src[(size_t)r * C + c];
    }
    __syncthreads();
#pragma unroll
    for (int i = 0; i < 4; i++) {
        int c = c0 + ty + i * 8, r = r0 + tx;
        if (c < C && r < R) dst[(size_t)c * R + r] = (__bf16)tile[tx][ty + i * 8];
    }
}

__global__ void transpose_f32_bf16(const float* __restrict__ src, __bf16* __restrict__ dst,
                                   int R, int C) {
    __shared__ float tile[32][33];
    int tx = threadIdx.x & 31, ty = threadIdx.x >> 5;
    int c0 = blockIdx.x * 32, r0 = blockIdx.y * 32;
#pragma unroll
    for (int i = 0; i < 4; i++) {
        int r = r0 + ty + i * 8, c = c0 + tx;
        if (r < R && c < C) tile[ty + i * 8][tx] = src[(size_t)r * C + c];
    }
    __syncthreads();
#pragma unroll
    for (int i = 0; i < 4; i++) {
        int c = c0 + ty + i * 8, r = r0 + tx;
        if (c < C && r < R) dst[(size_t)c * R + r] = (__bf16)tile[tx][ty + i * 8];
    }
}

// ---------------- MFMA GEMM: C[M,N] = A[M,K] @ BT[N,K]^T ----------------
// global_load_lds staging (m97 structure), LDK=32 no pad.
// MODE 0: f32 out (stride N), bias+act.  MODE 2: mega split (see epilogue).
template <int MODE>
__global__ __launch_bounds__(256, 2)
void gemm_bf16(const __bf16* __restrict__ A, int lda, const __bf16* __restrict__ BT,
               const float* __restrict__ bias, float* __restrict__ Cf,
               __bf16* __restrict__ Cb, int N, int K, int act) {
    __shared__ __align__(16) __bf16 As[128 * 32];
    __shared__ __align__(16) __bf16 Bs[128 * 32];
    const int tid = threadIdx.x;
    const int lane = tid & 63, wave = tid >> 6;
    const int bm = blockIdx.y * 128, bn = blockIdx.x * 128;
    const int wm = (wave >> 1) * 64, wn = (wave & 1) * 64;
    const int prow = lane >> 2, pk = (lane & 3) * 8;
    const __bf16* ApA = A + (size_t)(bm + wave * 32 + prow) * lda + pk;
    const __bf16* BpA = BT + (size_t)(bn + wave * 32 + prow) * K + pk;
    const bool bokA = (bn + wave * 32 + prow) < N;
    const bool bokB = (bn + wave * 32 + 16 + prow) < N;
    __bf16* AsD = As + wave * 1024;
    __bf16* BsD = Bs + wave * 1024;
    const int lm = lane & 15, lq = lane >> 4;
    f32x4 acc[4][4] = {};
    for (int k0 = 0; k0 < K; k0 += 32) {
        __syncthreads();
        gll16(ApA + k0, AsD);
        gll16(ApA + (size_t)16 * lda + k0, AsD + 512);
        if (bokA) gll16(BpA + k0, BsD);
        if (bokB) gll16(BpA + (size_t)16 * K + k0, BsD + 512);
        __syncthreads();
        bf16x8 af[4], bfr[4];
#pragma unroll
        for (int i = 0; i < 4; i++)
            af[i] = *(const bf16x8*)(As + (wm + i * 16 + lm) * 32 + lq * 8);
#pragma unroll
        for (int j = 0; j < 4; j++)
            bfr[j] = *(const bf16x8*)(Bs + (wn + j * 16 + lm) * 32 + lq * 8);
#pragma unroll
        for (int i = 0; i < 4; i++)
#pragma unroll
            for (int j = 0; j < 4; j++)
                acc[i][j] = MFMA16(af[i], bfr[j], acc[i][j]);
    }
#pragma unroll
    for (int j = 0; j < 4; j++) {
        int col = bn + wn + j * 16 + lm;
        if (col >= N) continue;
        float bv = (MODE == 0 && bias) ? bias[col] : 0.f;
#pragma unroll
        for (int i = 0; i < 4; i++) {
            int row0 = bm + wm + i * 16 + lq * 4;
#pragma unroll
            for (int rg = 0; rg < 4; rg++) {
                float v = acc[i][j][rg] + bv;
                int row = row0 + rg;
                if (MODE == 0) {
                    if (act == 1) v = tanhf(v);
                    else if (act == 2) v = 1.f / (1.f + __expf(-v));
                    Cf[(size_t)row * N + col] = v;
                } else {
                    if (col < 3072) {
                        Cf[(size_t)row * 3072 + col] = v;
                    } else {
                        float vv = v;
                        if (col < 3232) vv = tanhf(v);
                        else if (col >= 3456) vv = 1.f / (1.f + __expf(-v));
                        Cb[(size_t)row * 544 + (col - 3072)] = (__bf16)vv;
                    }
                }
            }
        }
    }
}

// ---------------- grouped down-projection GEMM (one launch, 5 segments) ----
struct GSeg { const __bf16* BT; const float* bias; float* Cf; int aoff, K, N, act, bx0; };
struct GB5 { GSeg s[5]; };

__global__ __launch_bounds__(256, 2)
void gemm_group(const __bf16* __restrict__ Abase, GB5 gb) {
    __shared__ __align__(16) __bf16 As[128 * 32];
    __shared__ __align__(16) __bf16 Bs[128 * 32];
    int e = 0;
    while (e + 1 < 5 && gb.s[e + 1].bx0 <= (int)blockIdx.x) e++;
    const GSeg sg = gb.s[e];
    const int K = sg.K, N = sg.N;
    const __bf16* A = Abase + sg.aoff;
    const int tid = threadIdx.x;
    const int lane = tid & 63, wave = tid >> 6;
    const int bm = blockIdx.y * 128, bn = (blockIdx.x - sg.bx0) * 128;
    const int wm = (wave >> 1) * 64, wn = (wave & 1) * 64;
    const int prow = lane >> 2, pk = (lane & 3) * 8;
    const __bf16* ApA = A + (size_t)(bm + wave * 32 + prow) * 544 + pk;
    const __bf16* BpA = sg.BT + (size_t)(bn + wave * 32 + prow) * K + pk;
    __bf16* AsD = As + wave * 1024;
    __bf16* BsD = Bs + wave * 1024;
    const int lm = lane & 15, lq = lane >> 4;
    f32x4 acc[4][4] = {};
    for (int k0 = 0; k0 < K; k0 += 32) {
        __syncthreads();
        gll16(ApA + k0, AsD);
        gll16(ApA + (size_t)16 * 544 + k0, AsD + 512);
        gll16(BpA + k0, BsD);
        gll16(BpA + (size_t)16 * K + k0, BsD + 512);
        __syncthreads();
        bf16x8 af[4], bfr[4];
#pragma unroll
        for (int i = 0; i < 4; i++)
            af[i] = *(const bf16x8*)(As + (wm + i * 16 + lm) * 32 + lq * 8);
#pragma unroll
        for (int j = 0; j < 4; j++)
            bfr[j] = *(const bf16x8*)(Bs + (wn + j * 16 + lm) * 32 + lq * 8);
#pragma unroll
        for (int i = 0; i < 4; i++)
#pragma unroll
            for (int j = 0; j < 4; j++)
                acc[i][j] = MFMA16(af[i], bfr[j], acc[i][j]);
    }
#pragma unroll
    for (int j = 0; j < 4; j++) {
        int col = bn + wn + j * 16 + lm;
        float bv = sg.bias ? sg.bias[col] : 0.f;
#pragma unroll
        for (int i = 0; i < 4; i++) {
            int row0 = bm + wm + i * 16 + lq * 4;
#pragma unroll
            for (int rg = 0; rg < 4; rg++) {
                float v = acc[i][j][rg] + bv;
                if (sg.act == 2) v = 1.f / (1.f + __expf(-v));
                sg.Cf[(size_t)(row0 + rg) * N + col] = v;
            }
        }
    }
}

// ---------------- prep for k/v (per (t,kvh)); mega row stride 3072 ----------------
__global__ __launch_bounds__(128)
void prep_kv(float* __restrict__ mega, float* __restrict__ kkO,
             const float* __restrict__ kfirst, const float* __restrict__ vfirst,
             const float* __restrict__ kmix, const float* __restrict__ vmix,
             const float* __restrict__ cosT, const float* __restrict__ sinT,
             const float* __restrict__ knw) {
    __shared__ float sh[128];
    __shared__ float sh2[2];
    int b = blockIdx.x;
    int t = b >> 2, kvh = b & 3;
    int n = threadIdx.x;
    size_t kbase = (size_t)t * 3072 + 2048 + kvh * 128;
    size_t vbase = (size_t)t * 3072 + 2560 + kvh * 128;
    size_t fbase = (size_t)t * 512 + kvh * 128;
    float x = mega[kbase + n];
    float ssq = block_sum_128(x * x, sh2);
    float kn = knw[n] * (x * rsqrtf(ssq * (1.f / 128.f) + 1e-6f));
    sh[n] = kn;
    __syncthreads();
    float rot = (n < 64) ? -sh[n + 64] : sh[n - 64];
    float c = cosT[(size_t)t * 128 + n], s = sinT[(size_t)t * 128 + n];
    float kr = kn * c + rot * s;
    float kf = kr + (kfirst[fbase + n] - kr) * kmix[fbase + n];
    float s2 = block_sum_128(kf * kf, sh2);
    float kkv = kf / fmaxf(sqrtf(s2), 1e-12f);
    float vv = mega[vbase + n];
    float vf = vv + (vfirst[fbase + n] - vv) * vmix[fbase + n];
    mega[kbase + n] = kf;
    kkO[fbase + n] = kkv;
    mega[vbase + n] = vf;
}

// ---------------- prep for r / wdec / c (per (t,h)) ----------------
__global__ __launch_bounds__(128)
void prep_r(float* __restrict__ mega, float* __restrict__ Wl,
            const float* __restrict__ rk, float* __restrict__ cOut,
            const float* __restrict__ cosT, const float* __restrict__ sinT,
            const float* __restrict__ rnw) {
    __shared__ float sh[128];
    __shared__ float sh2[2];
    int b = blockIdx.x;
    int t = b >> 4, h = b & 15;
    int kv = h >> 2;
    int n = threadIdx.x;
    size_t rbase = (size_t)t * 3072 + h * 128;
    float x = mega[rbase + n];
    float ssq = block_sum_128(x * x, sh2);
    float rn = rnw[n] * (x * rsqrtf(ssq * (1.f / 128.f) + 1e-6f));
    sh[n] = rn;
    __syncthreads();
    float rot = (n < 64) ? -sh[n + 64] : sh[n - 64];
    float c = cosT[(size_t)t * 128 + n], s = sinT[(size_t)t * 128 + n];
    float rr = rn * c + rot * s;
    mega[rbase + n] = rr;
    size_t wb_ = (size_t)t * 2048 + h * 128 + n;
    float z = Wl[wb_];
    float nz = -z;
    float sp = fmaxf(nz, 0.f) + log1pf(expf(-fabsf(nz)));
    float w = -sp - 0.5f;
    Wl[wb_] = expf(-expf(w));
    float pc = rr * mega[(size_t)t * 3072 + 2048 + kv * 128 + n] * rk[h * 128 + n];
    float cs = block_sum_128(pc, sh2);
    if (n == 0) cOut[b] = cs;
}

// =====================================================================
// Chunked scan, L=32, 64 chunks (WY/UT transform).
// =====================================================================

// ---- phase A: per (head, chunk) = 1024 blocks x 1 wave -------------
__global__ __launch_bounds__(64)
void scan_phaseA(const float* __restrict__ Wl, const float* __restrict__ megaF,
                 const float* __restrict__ aS, const float* __restrict__ kkB,
                 __bf16* __restrict__ ATt_g, __bf16* __restrict__ Rr_g,
                 __bf16* __restrict__ Bnt_g, __bf16* __restrict__ Knt_g,
                 __bf16* __restrict__ Vt_g, __bf16* __restrict__ Gbt_g,
                 __bf16* __restrict__ Gkt_g, float* __restrict__ Cloc_g,
                 float* __restrict__ cwL_g) {
    __shared__ __align__(16) __bf16 pool[27648];
    __bf16* Arm = pool;            // [32][136]
    __bf16* Brm = pool + 4352;     // [32][136]
    __bf16* Krm = pool + 8704;     // [32][136]
    __bf16* Rrm = pool + 13056;    // [32][136]
    __bf16* Vt  = pool + 17408;    // [128][40]
    __bf16* Mrm = pool + 22528;    // [32][40]
    __bf16* Mt  = pool + 23808;    // [32][40]
    __bf16* Prm = pool + 25088;    // [32][40]
    __bf16* Gtmp= pool + 26368;    // [32][40]
    __bf16* M2rm = pool + 4352;
    __bf16* M2t  = pool + 5632;
    __bf16* Xa   = pool + 6912;
    __bf16* Xb   = pool + 8192;
    __bf16* Tt   = pool + 9472;    // [t'][s] = T[s][t']   stride 40
    __bf16* PTt  = pool + 10752;   // [t'][s] = (P*T)[s][t']
    __bf16* Ant  = pool + 13056;   // [n][s] stride 32 (overlays Rrm after copy-out)

    const int l = threadIdx.x, lm = l & 15, lq = l >> 4;
    const int u = blockIdx.x, h = u >> 6, c = u & 63, kv = h >> 2;
    const int n0 = l, n1 = l + 64;

    float cw0 = 1.f, cw1 = 1.f;
    for (int t = 0; t < 32; ++t) {
        int tg = c * 32 + t;
        size_t hb = (size_t)tg * 2048 + h * 128;
        size_t mb = (size_t)tg * 3072;
        size_t kb = (size_t)tg * 512 + kv * 128;
        float wv0 = Wl[hb + n0], wv1 = Wl[hb + n1];
        float r0 = megaF[mb + h * 128 + n0], r1 = megaF[mb + h * 128 + n1];
        float q0 = kkB[kb + n0], q1 = kkB[kb + n1];
        float s0 = aS[hb + n0], s1 = aS[hb + n1];
        float k0 = megaF[mb + 2048 + kv * 128 + n0], k1 = megaF[mb + 2048 + kv * 128 + n1];
        float v0 = megaF[mb + 2560 + kv * 128 + n0], v1 = megaF[mb + 2560 + kv * 128 + n1];
        float cp0 = cw0, cp1 = cw1;
        cw0 *= wv0; cw1 *= wv1;
        float ic0 = 1.f / cw0, ic1 = 1.f / cw1;
        Arm[t * 136 + n0] = (__bf16)(-cp0 * q0);
        Arm[t * 136 + n1] = (__bf16)(-cp1 * q1);
        Brm[t * 136 + n0] = (__bf16)(q0 * s0 * ic0);
        Brm[t * 136 + n1] = (__bf16)(q1 * s1 * ic1);
        Krm[t * 136 + n0] = (__bf16)(k0 * ic0);
        Krm[t * 136 + n1] = (__bf16)(k1 * ic1);
        Rrm[t * 136 + n0] = (__bf16)(cw0 * r0);
        Rrm[t * 136 + n1] = (__bf16)(cw1 * r1);
        Vt[n0 * 40 + t] = (__bf16)v0;
        Vt[n1 * 40 + t] = (__bf16)v1;
    }
    cwL_g[(size_t)u * 128 + n0] = cw0;
    cwL_g[(size_t)u * 128 + n1] = cw1;
    __syncthreads();

    auto mmLL = [&](const __bf16* Ao, const __bf16* Bo, bool incl, __bf16* dTr, __bf16* dDir) {
#pragma unroll
        for (int ri = 0; ri < 2; ri++)
#pragma unroll
        for (int ci = 0; ci < 2; ci++) {
            f32x4 acc = {};
#pragma unroll
            for (int s = 0; s < 4; s++) {
                bf16x8 af = *(const bf16x8*)(Ao + (ri * 16 + lm) * 136 + s * 32 + lq * 8);
                bf16x8 bf = *(const bf16x8*)(Bo + (ci * 16 + lm) * 136 + s * 32 + lq * 8);
                acc = MFMA16(af, bf, acc);
            }
#pragma unroll
            for (int rg = 0; rg < 4; rg++) {
                int rr = ri * 16 + lq * 4 + rg, cc = ci * 16 + lm;
                bool keep = incl ? (cc <= rr) : (cc < rr);
                __bf16 bv = (__bf16)(keep ? acc[rg] : 0.f);
                if (dTr)  dTr[cc * 40 + rr] = bv;
                if (dDir) dDir[rr * 40 + cc] = bv;
            }
        }
    };
    mmLL(Arm, Brm, false, Mrm, Mt);
    mmLL(Arm, Krm, false, Prm, nullptr);
    mmLL(Rrm, Brm, true, nullptr, Gtmp);
    __syncthreads();
    for (int i = l; i < 512; i += 64) {
        int r = i >> 4, cp = i & 15;
        ((int*)(Gbt_g + (size_t)u * 1024))[i] = *(const int*)(Gtmp + r * 40 + cp * 2);
    }
    __syncthreads();
    mmLL(Rrm, Krm, true, nullptr, Gtmp);
    __syncthreads();
    for (int i = l; i < 512; i += 64) {
        int r = i >> 4, cp = i & 15;
        ((int*)(Gkt_g + (size_t)u * 1024))[i] = *(const int*)(Gtmp + r * 40 + cp * 2);
    }
    for (int i = l; i < 2048; i += 64) {
        int t = i >> 6, cp = i & 63;
        ((int*)(Rr_g + (size_t)u * 4096))[i] = *(const int*)(Rrm + t * 136 + cp * 2);
    }
    for (int i = l; i < 2048; i += 64) {
        int n = i >> 4, tp = i & 15;
        unsigned int lo = ((const unsigned short*)Brm)[(2 * tp) * 136 + n];
        unsigned int hi = ((const unsigned short*)Brm)[(2 * tp + 1) * 136 + n];
        ((unsigned int*)(Bnt_g + (size_t)u * 4096))[i] = lo | (hi << 16);
        unsigned int lo2 = ((const unsigned short*)Krm)[(2 * tp) * 136 + n];
        unsigned int hi2 = ((const unsigned short*)Krm)[(2 * tp + 1) * 136 + n];
        ((unsigned int*)(Knt_g + (size_t)u * 4096))[i] = lo2 | (hi2 << 16);
    }
    for (int i = l; i < 2048; i += 64) {
        int n = i >> 4, tp = i & 15;
        ((int*)(Vt_g + (size_t)u * 4096))[i] = *(const int*)(Vt + n * 40 + tp * 2);
    }
    __syncthreads();

    // Xa = I + M ; Ant = A~^T (into freed Rrm region, stride 32)
    for (int i = l; i < 1024; i += 64) {
        int s = i >> 5, t = i & 31;
        Xa[s * 40 + t] = (s == t) ? (__bf16)1.f : Mrm[s * 40 + t];
    }
    for (int i = l; i < 4096; i += 64) {
        int s = i & 31, n = i >> 5;
        Ant[n * 32 + s] = Arm[s * 136 + n];
    }
    __syncthreads();

    auto mat32 = [&](const __bf16* Ao, const __bf16* Bo, const __bf16* accIn,
                     __bf16* oRm, __bf16* oT) {
#pragma unroll
        for (int ri = 0; ri < 2; ri++)
#pragma unroll
        for (int ci = 0; ci < 2; ci++) {
            f32x4 acc = {};
            if (accIn) {
#pragma unroll
                for (int rg = 0; rg < 4; rg++)
                    acc[rg] = (float)accIn[(ri * 16 + lq * 4 + rg) * 40 + ci * 16 + lm];
            }
            bf16x8 af = *(const bf16x8*)(Ao + (ri * 16 + lm) * 40 + lq * 8);
            bf16x8 bf = *(const bf16x8*)(Bo + (ci * 16 + lm) * 40 + lq * 8);
            acc = MFMA16(af, bf, acc);
#pragma unroll
            for (int rg = 0; rg < 4; rg++) {
                int rr = ri * 16 + lq * 4 + rg, cc = ci * 16 + lm;
                __bf16 bv = (__bf16)acc[rg];
                if (oRm) oRm[rr * 40 + cc] = bv;
                if (oT)  oT[cc * 40 + rr] = bv;
            }
        }
        __syncthreads();
    };
    mat32(Mrm, Mt, nullptr, M2rm, M2t);
    mat32(Xa, M2t, Xa, Xb, nullptr);
    mat32(M2rm, M2t, nullptr, Mrm, Mt);
    mat32(Xb, Mt, Xb, Xa, nullptr);
    mat32(Mrm, Mt, nullptr, M2rm, M2t);
    mat32(Xa, M2t, Xa, Xb, nullptr);
    mat32(M2rm, M2t, nullptr, Mrm, Mt);
    mat32(Xb, Mt, Xb, nullptr, Tt);
    mat32(Tt, Prm, nullptr, PTt, nullptr);

    // ATt[t'][n] = sum_s T[s][t'] * A~[s][n] via MFMA (A=Tt frag, B=Ant frag)
#pragma unroll
    for (int ti = 0; ti < 2; ti++) {
        bf16x8 af = *(const bf16x8*)(Tt + (ti * 16 + lm) * 40 + lq * 8);
#pragma unroll
        for (int ni = 0; ni < 8; ni++) {
            f32x4 accv = {};
            bf16x8 bfv = *(const bf16x8*)(Ant + (ni * 16 + lm) * 32 + lq * 8);
            accv = MFMA16(af, bfv, accv);
#pragma unroll
            for (int rg = 0; rg < 4; rg++)
                ATt_g[(size_t)u * 4096 + (ti * 16 + lq * 4 + rg) * 128 + ni * 16 + lm] = (__bf16)accv[rg];
        }
    }
    // C_loc = V * (P T)
#pragma unroll
    for (int ii = 0; ii < 8; ii++)
#pragma unroll
    for (int ti = 0; ti < 2; ti++) {
        f32x4 acc = {};
        bf16x8 af = *(const bf16x8*)(Vt + (ii * 16 + lm) * 40 + lq * 8);
        bf16x8 bf = *(const bf16x8*)(PTt + (ti * 16 + lm) * 40 + lq * 8);
        acc = MFMA16(af, bf, acc);
#pragma unroll
        for (int rg = 0; rg < 4; rg++)
            Cloc_g[(size_t)u * 4096 + (ii * 16 + lq * 4 + rg) * 32 + ti * 16 + lm] = acc[rg];
    }
}

// ---- phase B v2: 4 waves/block; wave w owns state cols [w*32, w*32+32) ----
struct OpsV {
    bf16x8 at[2], bn[2], kn[2], vf;
    f32x4 cl[2];
    float cw[2];
};

__global__ __launch_bounds__(256, 2)
void scan_phaseB(const __bf16* __restrict__ ATt_g, const __bf16* __restrict__ Bnt_g,
                 const __bf16* __restrict__ Knt_g, const __bf16* __restrict__ Vt_g,
                 const float* __restrict__ Cloc_g, const float* __restrict__ cwL_g,
                 __bf16* __restrict__ Sg, __bf16* __restrict__ Cg) {
    __shared__ __align__(16) __bf16 Ssl[4][16 * 40];   // per-wave S slice, stride 40
    __shared__ __align__(16) float Pl[2][4][16 * 36];  // C partials, stride 36
    const int h = blockIdx.y, i0 = blockIdx.x * 16;
    const int tid = threadIdx.x, w = tid >> 6, l = tid & 63;
    const int lm = l & 15, lq = l >> 4;
    f32x4 st[2] = {};

    auto loadOps = [&](int c, OpsV& o) {
        size_t u = (size_t)h * 64 + c;
#pragma unroll
        for (int j = 0; j < 2; j++) {
            o.at[j] = *(const bf16x8*)(ATt_g + u * 4096 + (size_t)(j * 16 + lm) * 128 + w * 32 + lq * 8);
            o.bn[j] = *(const bf16x8*)(Bnt_g + u * 4096 + (size_t)(w * 32 + j * 16 + lm) * 32 + lq * 8);
            o.kn[j] = *(const bf16x8*)(Knt_g + u * 4096 + (size_t)(w * 32 + j * 16 + lm) * 32 + lq * 8);
            o.cw[j] = cwL_g[u * 128 + w * 32 + j * 16 + lm];
        }
        o.vf = *(const bf16x8*)(Vt_g + u * 4096 + (size_t)(i0 + lm) * 32 + lq * 8);
        o.cl[0] = *(const f32x4*)(Cloc_g + u * 4096 + (size_t)(i0 + lm) * 32 + lq * 8);
        o.cl[1] = *(const f32x4*)(Cloc_g + u * 4096 + (size_t)(i0 + lm) * 32 + lq * 8 + 4);
    };

    auto compute = [&](int c, const OpsV& o) {
        size_t u = (size_t)h * 64 + c;
        int buf = c & 1;
        // S (f32 C-layout) -> bf16 LDS slice [i][n_local]  (wave-local, in-order DS)
#pragma unroll
        for (int j = 0; j < 2; j++)
#pragma unroll
            for (int rg = 0; rg < 4; rg++)
                Ssl[w][(lq * 4 + rg) * 40 + j * 16 + lm] = (__bf16)st[j][rg];
        bf16x8 saf = *(const bf16x8*)(&Ssl[w][lm * 40 + lq * 8]);  // A-frag [i=lm][k=n]
        // partial C = S0slice * ATslice  (C-layout, t' on lm)
        f32x4 zz = {};
        f32x4 pc0 = MFMA16(saf, o.at[0], zz);
        f32x4 pc1 = MFMA16(saf, o.at[1], zz);
        // dump S0 slice (row-major [i][n]) — off critical path
        *(bf16x8*)(Sg + u * 16384 + (size_t)(i0 + lm) * 128 + w * 32 + lq * 8) = saf;
#pragma unroll
        for (int rg = 0; rg < 4; rg++) {
            Pl[buf][w][(lq * 4 + rg) * 36 + lm] = pc0[rg];
            Pl[buf][w][(lq * 4 + rg) * 36 + 16 + lm] = pc1[rg];
        }
        __syncthreads();
        // reduce partials + Cloc -> C in A-frag layout [i=lm][t=lq*8+j]
        f32x4 s0 = o.cl[0], s1 = o.cl[1];
#pragma unroll
        for (int ww = 0; ww < 4; ww++) {
            s0 += *(const f32x4*)(&Pl[buf][ww][lm * 36 + lq * 8]);
            s1 += *(const f32x4*)(&Pl[buf][ww][lm * 36 + lq * 8 + 4]);
        }
        bf16x8 cf;
#pragma unroll
        for (int j = 0; j < 4; j++) { cf[j] = (__bf16)s0[j]; cf[4 + j] = (__bf16)s1[j]; }
        if (w == 0)
            *(bf16x8*)(Cg + u * 4096 + (size_t)(i0 + lm) * 32 + lq * 8) = cf;
        // S = (S0 + C*B^T + V*K^T) * cwL   (wave's col slice)
#pragma unroll
        for (int j = 0; j < 2; j++) {
            f32x4 t = MFMA16(o.vf, o.kn[j], st[j]);
            t = MFMA16(cf, o.bn[j], t);
            float cwv = o.cw[j];
#pragma unroll
            for (int rg = 0; rg < 4; rg++) st[j][rg] = t[rg] * cwv;
        }
    };

    OpsV A, B;
    loadOps(0, A);
    loadOps(1, B);
    for (int c = 0; c < 64; c += 2) {
        compute(c, A);
        if (c + 2 < 64) loadOps(c + 2, A);
        compute(c + 1, B);
        if (c + 3 < 64) loadOps(c + 3, B);
    }
}

// ---- phase C: Y = S0*R^ + C*Gb + V*Gk, fused output gating ----
__global__ __launch_bounds__(64)
void scan_phaseC(const __bf16* __restrict__ Sg, const __bf16* __restrict__ Cg,
                 const __bf16* __restrict__ Rr_g, const __bf16* __restrict__ Vt_g,
                 const __bf16* __restrict__ Gbt_g, const __bf16* __restrict__ Gkt_g,
                 const float* __restrict__ cB, const float* __restrict__ megaF,
                 const float* __restrict__ gB, __bf16* __restrict__ out) {
    __shared__ float Ybuf[32 * 18];
    const int bx = blockIdx.x, h = blockIdx.y;
    const int c = bx >> 3, i0 = (bx & 7) * 16;
    const int l = threadIdx.x, lm = l & 15, lq = l >> 4;
    const size_t u = (size_t)h * 64 + c;
    bf16x8 saf[4];
#pragma unroll
    for (int s = 0; s < 4; s++)
        saf[s] = *(const bf16x8*)(Sg + u * 16384 + (size_t)(i0 + lm) * 128 + s * 32 + lq * 8);
    bf16x8 cf = *(const bf16x8*)(Cg + u * 4096 + (size_t)(i0 + lm) * 32 + lq * 8);
    bf16x8 vf = *(const bf16x8*)(Vt_g + u * 4096 + (size_t)(i0 + lm) * 32 + lq * 8);
#pragma unroll
    for (int ti = 0; ti < 2; ti++) {
        f32x4 acc = {};
#pragma unroll
        for (int s = 0; s < 4; s++) {
            bf16x8 rp = *(const bf16x8*)(Rr_g + u * 4096 + (ti * 16 + lm) * 128 + s * 32 + lq * 8);
            acc = MFMA16(saf[s], rp, acc);
        }
        bf16x8 gb = *(const bf16x8*)(Gbt_g + u * 1024 + (ti * 16 + lm) * 32 + lq * 8);
        acc = MFMA16(cf, gb, acc);
        bf16x8 gk = *(const bf16x8*)(Gkt_g + u * 1024 + (ti * 16 + lm) * 32 + lq * 8);
        acc = MFMA16(vf, gk, acc);
#pragma unroll
        for (int rg = 0; rg < 4; rg++)
            Ybuf[(ti * 16 + lm) * 18 + lq * 4 + rg] = acc[rg];
    }
    __syncthreads();
    const int kv = h >> 2;
#pragma unroll
    for (int pass = 0; pass < 8; pass++) {
        int t = pass * 4 + lq;
        int tg = c * 32 + t;
        int col = h * 128 + i0 + lm;
        float yv = Ybuf[t * 18 + lm];
        float cv = cB[tg * 16 + h];
        float vv = megaF[(size_t)tg * 3072 + 2560 + kv * 128 + i0 + lm];
        float gg = gB[(size_t)tg * 2048 + col];
        out[(size_t)tg * 2048 + col] = (__bf16)((yv + cv * vv) * gg);
    }
}

// ---------------- orchestration ----------------
extern "C" void kernel_launch(void* const* d_in, const int* in_sizes, int n_in,
                              void* d_out, int out_size, void* d_ws, size_t ws_size,
                              hipStream_t stream) {
    (void)in_sizes; (void)n_in; (void)out_size; (void)ws_size;
    const float* x      = (const float*)d_in[0];
    const float* vfirst = (const float*)d_in[1];
    const float* kfirst = (const float*)d_in[2];
    const float* amask  = (const float*)d_in[3];
    const float* cosT   = (const float*)d_in[4];
    const float* sinT   = (const float*)d_in[5];
    const float* w0     = (const float*)d_in[6];
    const float* w1     = (const float*)d_in[7];
    const float* w2     = (const float*)d_in[8];
    const float* a0     = (const float*)d_in[9];
    const float* a1     = (const float*)d_in[10];
    const float* a2     = (const float*)d_in[11];
    const float* v0     = (const float*)d_in[12];
    const float* v1     = (const float*)d_in[13];
    const float* v2     = (const float*)d_in[14];
    const float* k0     = (const float*)d_in[15];
    const float* k1     = (const float*)d_in[16];
    const float* k2     = (const float*)d_in[17];
    const float* g1     = (const float*)d_in[18];
    const float* g2     = (const float*)d_in[19];
    const float* rk     = (const float*)d_in[20];
    const float* rnw    = (const float*)d_in[21];
    const float* knw    = (const float*)d_in[22];
    const float* W_r    = (const float*)d_in[23];
    const float* W_k    = (const float*)d_in[24];
    const float* W_v    = (const float*)d_in[25];
    const float* W_o    = (const float*)d_in[26];

    char* p = (char*)d_ws;
    auto take = [&](size_t bytes) { char* r = p; p += (bytes + 255) & ~(size_t)255; return r; };
    __bf16* arena   = (__bf16*)take((size_t)3616 * 2048 * 2);
    __bf16* xmb     = (__bf16*)take((size_t)T_ * C_ * 2);
    float*  megaF   = (float*)take((size_t)T_ * 3072 * 4);
    __bf16* megaB   = (__bf16*)take((size_t)T_ * 544 * 2);
    __bf16* w2T     = (__bf16*)take((size_t)2048 * 160 * 2);
    __bf16* a2T     = (__bf16*)take((size_t)2048 * 96 * 2);
    __bf16* v2T     = (__bf16*)take((size_t)512 * 64 * 2);
    __bf16* k2T     = (__bf16*)take((size_t)512 * 64 * 2);
    __bf16* g2T     = (__bf16*)take((size_t)2048 * 160 * 2);
    float*  Wl      = (float*)take((size_t)T_ * 2048 * 4);   // wdec; reused as Sg
    float*  aS      = (float*)take((size_t)T_ * 2048 * 4);   // a; tail of Sg
    float*  gB      = (float*)take((size_t)T_ * 2048 * 4);
    float*  kkB     = (float*)take((size_t)T_ * 512 * 4);    // kk; reused as Cg
    float*  vmx     = (float*)take((size_t)T_ * 512 * 4);    // tail of Cg
    float*  kmx     = (float*)take((size_t)T_ * 512 * 4);
    float*  cB      = (float*)take((size_t)T_ * H_ * 4);
    __bf16* ATt_g   = (__bf16*)take((size_t)1024 * 4096 * 2);
    __bf16* Rr_g    = (__bf16*)take((size_t)1024 * 4096 * 2);
    __bf16* Bnt_g   = (__bf16*)take((size_t)1024 * 4096 * 2);
    __bf16* Knt_g   = (__bf16*)take((size_t)1024 * 4096 * 2);
    __bf16* Vt_g    = (__bf16*)take((size_t)1024 * 4096 * 2);
    __bf16* Gbt_g   = (__bf16*)take((size_t)1024 * 1024 * 2);
    __bf16* Gkt_g   = (__bf16*)take((size_t)1024 * 1024 * 2);
    float*  Cloc_g  = (float*)take((size_t)1024 * 4096 * 4);
    float*  cwL_g   = (float*)take((size_t)1024 * 128 * 4);
    __bf16* Sg = (__bf16*)Wl;
    __bf16* Cg = (__bf16*)kkB;

    xm_to_bf16<<<(T_ * C_ / 4) / 256, 256, 0, stream>>>(x, amask, xmb);

    TrBatch tb;
    {
        const float* srcs[13] = {W_r, W_k, W_v, w1, a1, v1, k1, g1, w2, a2, v2, k2, g2};
        __bf16* dsts[13] = {arena, arena + (size_t)2048 * 2048, arena + (size_t)2560 * 2048,
                            arena + (size_t)3072 * 2048, arena + (size_t)3232 * 2048,
                            arena + (size_t)3328 * 2048, arena + (size_t)3392 * 2048,
                            arena + (size_t)3456 * 2048, w2T, a2T, v2T, k2T, g2T};
        int Rs[13] = {2048, 2048, 2048, 2048, 2048, 2048, 2048, 2048, 160, 96, 64, 64, 160};
        int Cs[13] = {2048, 512, 512, 160, 96, 64, 64, 160, 2048, 2048, 512, 512, 2048};
        int cum = 0;
        for (int e = 0; e < 13; e++) {
            tb.d[e].src = srcs[e]; tb.d[e].dst = dsts[e];
            tb.d[e].R = Rs[e]; tb.d[e].C = Cs[e]; tb.d[e].tileStart = cum;
            cum += ((Rs[e] + 31) / 32) * ((Cs[e] + 31) / 32);
        }
        tb.n = 13;
        transpose_batch<<<cum, 256, 0, stream>>>(tb);
    }

    gemm_bf16<2><<<dim3(29, 16), 256, 0, stream>>>(xmb, 2048, arena, nullptr, megaF, megaB, 3616, 2048, 0);

    GB5 gb;
    gb.s[0] = {w2T, w0, Wl,  0,   160, 2048, 0, 0};
    gb.s[1] = {a2T, a0, aS,  160, 96,  2048, 2, 16};
    gb.s[2] = {v2T, v0, vmx, 256, 64,  512,  2, 32};
    gb.s[3] = {k2T, k0, kmx, 320, 64,  512,  2, 36};
    gb.s[4] = {g2T, nullptr, gB, 384, 160, 2048, 0, 40};
    gemm_group<<<dim3(56, 16), 256, 0, stream>>>(megaB, gb);

    prep_kv<<<T_ * KVH_, 128, 0, stream>>>(megaF, kkB, kfirst, vfirst, kmx, vmx, cosT, sinT, knw);
    prep_r<<<T_ * H_, 128, 0, stream>>>(megaF, Wl, rk, cB, cosT, sinT, rnw);

    scan_phaseA<<<1024, 64, 0, stream>>>(Wl, megaF, aS, kkB, ATt_g, Rr_g, Bnt_g, Knt_g,
                                         Vt_g, Gbt_g, Gkt_g, Cloc_g, cwL_g);
    scan_phaseB<<<dim3(8, 16), 256, 0, stream>>>(ATt_g, Bnt_g, Knt_g, Vt_g, Cloc_g, cwL_g, Sg, Cg);
    scan_phaseC<<<dim3(512, 16), 64, 0, stream>>>(Sg, Cg, Rr_g, Vt_g, Gbt_g, Gkt_g,
                                                  cB, megaF, gB, xmb);

    transpose_f32_bf16<<<dim3(64, 64), 256, 0, stream>>>(W_o, arena, 2048, 2048);
    gemm_bf16<0><<<dim3(16, 16), 256, 0, stream>>>(xmb, 2048, arena, nullptr, (float*)d_out, nullptr, 2048, 2048, 0);
}